// Round 13
// baseline (33636.316 us; speedup 1.0000x reference)
//
#include <hip/hip_runtime.h>
#include <math.h>

// ============================================================================
// LARNN forward, MI355X — persistent kernel, fence-free sc1 (round-11 base,
// verified 16.06 ms). ALL-F32 (bf16 diverges — chaotic recurrence). Det. BN.
// Round 13 = round 11 EXACTLY, except the GEMM microtile:
//   4x4 microtile, 64x128 tiles (was 2x4 / 64x64). r11 was LDS-BW-bound
//   (24 B/thread/k for 8 FMA = 20us/tile vs 6.8us FMA floor). Now: A stored
//   k-major (broadcast f4 read, ~free) + B contiguous f4 -> 1KB/wave/k =
//   FMA-balanced. Named-value prefetch only (reg arrays spill — rule #20).
//   Barrier/phases/attention/gates unchanged from r11. addm only in P5.
// ============================================================================

#define T_  128
#define B_  256
#define F_  128
#define H_  512
#define W_  16
#define H4_ 2048
#define EPS_ 1e-5f
#define BH_ (B_*H_)
#define NBLK 256
#define NTHR 512
#define FSTRIDE 32   // uints per flag (128B line)

typedef __attribute__((ext_vector_type(4))) float f4;
typedef unsigned long long u64;

__device__ __forceinline__ float eluf(float x){ return x > 0.f ? x : expf(x) - 1.f; }
__device__ __forceinline__ float sigf(float x){ return 1.f / (1.f + expf(-x)); }

// ---- LLC-coherent (sc1) relaxed accessors: no cache maintenance emitted ----
__device__ __forceinline__ f4 ld_c(const float* p) {
  union { f4 v; u64 q[2]; } u;
  u.q[0] = __hip_atomic_load((const u64*)p,     __ATOMIC_RELAXED, __HIP_MEMORY_SCOPE_AGENT);
  u.q[1] = __hip_atomic_load((const u64*)p + 1, __ATOMIC_RELAXED, __HIP_MEMORY_SCOPE_AGENT);
  return u.v;
}
__device__ __forceinline__ void st_c(float* p, f4 v) {
  union { f4 v; u64 q[2]; } u; u.v = v;
  __hip_atomic_store((u64*)p,     u.q[0], __ATOMIC_RELAXED, __HIP_MEMORY_SCOPE_AGENT);
  __hip_atomic_store((u64*)p + 1, u.q[1], __ATOMIC_RELAXED, __HIP_MEMORY_SCOPE_AGENT);
}
__device__ __forceinline__ float ldf_c(const float* p) {
  unsigned u = __hip_atomic_load((const unsigned*)p, __ATOMIC_RELAXED, __HIP_MEMORY_SCOPE_AGENT);
  return __uint_as_float(u);
}
__device__ __forceinline__ void stf_c(float* p, float v) {
  __hip_atomic_store((unsigned*)p, __float_as_uint(v), __ATOMIC_RELAXED, __HIP_MEMORY_SCOPE_AGENT);
}

struct Params {
  const float *x, *W_ih, *b_ih, *W_hh, *Wq_in, *bq_in, *Wq, *bq, *Wk, *bk,
              *Wv, *bv, *Wo, *bo, *W_ac, *b_ac, *g_att, *be_att, *g_post, *be_post;
  float *out, *c, *q, *Qh, *ctx, *attp, *hv, *pre, *Kbuf, *Vbuf, *stA, *stP;
  unsigned *gen, *arr;
};

// Round-7/11 barrier: flag store + block-0 parallel aggregation + gen release.
__device__ __forceinline__ void gbar(unsigned* arr, unsigned* gen, unsigned g) {
  asm volatile("s_waitcnt vmcnt(0) lgkmcnt(0)" ::: "memory");
  __syncthreads();
  const int tid = threadIdx.x;
  if (tid == 0)
    __hip_atomic_store(&arr[blockIdx.x * FSTRIDE], g, __ATOMIC_RELAXED, __HIP_MEMORY_SCOPE_AGENT);
  if (blockIdx.x == 0) {
    if (tid < NBLK) {
      while (__hip_atomic_load(&arr[tid * FSTRIDE], __ATOMIC_RELAXED, __HIP_MEMORY_SCOPE_AGENT) < g)
        __builtin_amdgcn_s_sleep(1);
    }
    __syncthreads();
    if (tid == 0)
      __hip_atomic_store(gen, g, __ATOMIC_RELAXED, __HIP_MEMORY_SCOPE_AGENT);
  } else {
    if (tid == 0) {
      while (__hip_atomic_load(gen, __ATOMIC_RELAXED, __HIP_MEMORY_SCOPE_AGENT) < g)
        __builtin_amdgcn_s_sleep(1);
    }
  }
  __syncthreads();
}

// BN scale/shift from single-partial stats stP[2][512] (gates output).
__device__ __forceinline__ void prepP(const float* stP, const float* gn, const float* be,
                                      float* scl, float* shf, int tid) {
  if (tid < H_) {
    float S  = ldf_c(stP + tid);
    float S2 = ldf_c(stP + H_ + tid);
    float mu  = S * (1.f / B_);
    float var = S2 * (1.f / B_) - mu * mu;
    float sc  = rsqrtf(var + EPS_) * gn[tid];
    scl[tid] = sc; shf[tid] = be[tid] - mu * sc;
  }
}

// BN scale/shift from 4-way partial stats stA[4][2][512] (Wo GEMM output).
__device__ __forceinline__ void prepA(const float* stA, const float* gn, const float* be,
                                      float* scl, float* shf, int tid) {
  if (tid < H_) {
    float S  = ldf_c(stA + tid) + ldf_c(stA + 1024 + tid) + ldf_c(stA + 2048 + tid) + ldf_c(stA + 3072 + tid);
    float S2 = ldf_c(stA + 512 + tid) + ldf_c(stA + 1536 + tid) + ldf_c(stA + 2560 + tid) + ldf_c(stA + 3584 + tid);
    float mu  = S * (1.f / B_);
    float var = S2 * (1.f / B_) - mu * mu;
    float sc  = rsqrtf(var + EPS_) * gn[tid];
    scl[tid] = sc; shf[tid] = be[tid] - mu * sc;
  }
}

// ---------------------------------------------------------------------------
// 64x128 output tile, K-concat of up to 2 segments, 512 threads, 4x4 microtile.
// As k-major [2][32][68] (transposed; A-read = broadcast f4). Bs [2][32][132].
// LDS double-buffered; ONE sync per 32-k slab. Named-value prefetch:
// A depth-2 (aN1,aN2), B depth-1 (bNa,bNb). No register arrays.
// ---------------------------------------------------------------------------
struct GJ {
  const float* A1; int lda1; int K1; int nrm1; int cg1;
  const float* A2; int lda2; int K2; int nrm2; int cg2;
  const float* W1; const float* W2;    // [K][N] row-major, stride N (plain)
  const float* b1; const float* b2; const float* addm;
  float* out; float* stats;
  int N; int m0; int n0; int doElu;
};

__device__ void gemm_tile(const GJ& J, int tid,
                          float (*As)[32][68], float (*Bs)[32][132],
                          const float* scl, const float* shf) {
  const int arow = tid >> 3, akq = (tid & 7) * 4;    // A stage: 1 f4/thread
  const int bkk = tid >> 5, bnn = (tid & 31) * 4;    // B stage: 2 f4/thread
  const int ty = tid >> 5, tx = tid & 31;            // microtile 4x4

  f4 z = {0.f, 0.f, 0.f, 0.f};
  f4 acc0 = z, acc1 = z, acc2 = z, acc3 = z;

  f4 am0 = z, am1 = z, am2 = z, am3 = z;
  if (J.addm) {
    am0 = ld_c(J.addm + (size_t)(J.m0 + ty * 4)     * J.N + J.n0 + tx * 4);
    am1 = ld_c(J.addm + (size_t)(J.m0 + ty * 4 + 1) * J.N + J.n0 + tx * 4);
    am2 = ld_c(J.addm + (size_t)(J.m0 + ty * 4 + 2) * J.N + J.n0 + tx * 4);
    am3 = ld_c(J.addm + (size_t)(J.m0 + ty * 4 + 3) * J.N + J.n0 + tx * 4);
  }

  int buf = 0;
  for (int s = 0; s < 2; ++s) {
    const float* A = s ? J.A2 : J.A1;
    if (!A) break;
    const float* Wp  = s ? J.W2 : J.W1;
    const int K      = s ? J.K2 : J.K1;
    const int lda    = s ? J.lda2 : J.lda1;
    const int nrm    = s ? J.nrm2 : J.nrm1;
    const int cg     = s ? J.cg2 : J.cg1;
    const int nsl    = K >> 5;

    const float* aBase = A + (size_t)(J.m0 + arow) * lda + akq;
    const float* wBase = Wp + (size_t)bkk * J.N + J.n0 + bnn;
    const size_t wSlab = (size_t)32 * J.N;

    // prologue: named-value prefetch (A depth 2; B rows bkk & bkk+16 depth 1)
    f4 aN1 = cg ? ld_c(aBase) : *(const f4*)aBase;
    f4 aN2 = (nsl > 1) ? (cg ? ld_c(aBase + 32) : *(const f4*)(aBase + 32)) : aN1;
    f4 bNa = *(const f4*)wBase;
    f4 bNb = *(const f4*)(wBase + (size_t)16 * J.N);

    for (int sl = 0; sl < nsl; ++sl) {
      f4 aCur = aN1; aN1 = aN2;
      f4 bCa = bNa, bCb = bNb;
      if (sl + 2 < nsl) {
        const float* ap = aBase + (size_t)(sl + 2) * 32;
        aN2 = cg ? ld_c(ap) : *(const f4*)ap;
      }
      if (sl + 1 < nsl) {
        const float* wp = wBase + (size_t)(sl + 1) * wSlab;
        bNa = *(const f4*)wp;
        bNb = *(const f4*)(wp + (size_t)16 * J.N);
      }
      if (nrm) {
        #pragma unroll
        for (int i = 0; i < 4; ++i) {
          int gk = sl * 32 + akq + i;
          aCur[i] = aCur[i] * scl[gk] + shf[gk];
        }
      }
      // A: transposed store (k-major); 4 scalar stores, ~4-way conflict,
      // once per slab (negligible). B: 2 contiguous f4 stores.
      #pragma unroll
      for (int i = 0; i < 4; ++i) As[buf][akq + i][arow] = aCur[i];
      *(f4*)&Bs[buf][bkk][bnn] = bCa;
      *(f4*)&Bs[buf][bkk + 16][bnn] = bCb;
      __syncthreads();
      #pragma unroll
      for (int k = 0; k < 32; ++k) {
        f4 av = *(const f4*)&As[buf][k][ty * 4];   // broadcast (lanes share addr)
        f4 bv = *(const f4*)&Bs[buf][k][tx * 4];
        #pragma unroll
        for (int j = 0; j < 4; ++j) {
          acc0[j] = fmaf(av[0], bv[j], acc0[j]);
          acc1[j] = fmaf(av[1], bv[j], acc1[j]);
          acc2[j] = fmaf(av[2], bv[j], acc2[j]);
          acc3[j] = fmaf(av[3], bv[j], acc3[j]);
        }
      }
      buf ^= 1;
    }
  }

  const int r0 = J.m0 + ty * 4, c0 = J.n0 + tx * 4;
  f4 bias = z;
  if (J.b1) bias += *(const f4*)(J.b1 + c0);
  if (J.b2) bias += *(const f4*)(J.b2 + c0);
  f4 v0 = acc0 + bias, v1 = acc1 + bias, v2 = acc2 + bias, v3 = acc3 + bias;
  if (J.addm) { v0 += am0; v1 += am1; v2 += am2; v3 += am3; }
  if (J.doElu) {
    #pragma unroll
    for (int j = 0; j < 4; ++j) {
      v0[j] = eluf(v0[j]); v1[j] = eluf(v1[j]);
      v2[j] = eluf(v2[j]); v3[j] = eluf(v3[j]);
    }
  }
  st_c(J.out + (size_t)r0 * J.N + c0, v0);
  st_c(J.out + (size_t)(r0 + 1) * J.N + c0, v1);
  st_c(J.out + (size_t)(r0 + 2) * J.N + c0, v2);
  st_c(J.out + (size_t)(r0 + 3) * J.N + c0, v3);

  if (J.stats) {   // deterministic per-64-row-tile column partials (128 cols)
    float* Af = (float*)As;    // 2048 floats needed; 4352 available
    float* Bf = (float*)Bs;    // 8448 available
    __syncthreads();
    #pragma unroll
    for (int j = 0; j < 4; ++j) {
      Af[ty * 128 + tx * 4 + j] = v0[j] + v1[j] + v2[j] + v3[j];
      Bf[ty * 128 + tx * 4 + j] = v0[j]*v0[j] + v1[j]*v1[j] + v2[j]*v2[j] + v3[j]*v3[j];
    }
    __syncthreads();
    if (tid < 128) {
      float S = 0.f, S2 = 0.f;
      #pragma unroll
      for (int y = 0; y < 16; ++y) { S += Af[y * 128 + tid]; S2 += Bf[y * 128 + tid]; }
      const int tm = J.m0 >> 6;
      stf_c(J.stats + tm * 1024 + J.n0 + tid, S);
      stf_c(J.stats + tm * 1024 + 512 + J.n0 + tid, S2);
    }
  }
}

__global__ __launch_bounds__(NTHR, 1) void larnn(Params P) {
  __shared__ float As[2][32][68];
  __shared__ float Bs[2][32][132];
  __shared__ float scl[H_], shf[H_];
  __shared__ float Qs[H_];
  __shared__ float sc_[8][16], aw_[8][16];

  const int bid = blockIdx.x, tid = threadIdx.x;
  unsigned g = 0;

  for (int t = 0; t < T_; ++t) {
    const float* xt = P.x + (size_t)t * B_ * F_;
    const int slot = (t - 1) & 15;

    // ===== P1: q(16) | K-ring(16) | V-ring(16) | preHF(64) | out[t-1](32) =====
    if (bid < 16) {
      if (t > 0) { prepP(P.stP, P.g_post, P.be_post, scl, shf, tid); __syncthreads(); }
      GJ J = {}; J.A1 = xt; J.lda1 = F_; J.K1 = F_;
      if (t > 0) { J.A2 = P.hv; J.lda2 = H_; J.K2 = H_; J.nrm2 = 1; J.cg2 = 1; }
      J.W1 = P.Wq_in; J.W2 = P.Wq_in + (size_t)F_ * H_;
      J.b1 = P.bq_in; J.out = P.q; J.N = H_;
      J.m0 = (bid >> 2) * 64; J.n0 = (bid & 3) * 128; J.doElu = 1;
      gemm_tile(J, tid, As, Bs, scl, shf);
    } else if (bid < 32) {
      int l = bid - 16;
      GJ J = {}; J.A1 = P.c; J.lda1 = H_; J.K1 = H_; J.cg1 = 1;
      J.W1 = P.Wk; J.b1 = P.bk; J.out = P.Kbuf + (size_t)slot * BH_; J.N = H_;
      J.m0 = (l >> 2) * 64; J.n0 = (l & 3) * 128; J.doElu = 1;
      gemm_tile(J, tid, As, Bs, scl, shf);
    } else if (bid < 48) {
      int l = bid - 32;
      GJ J = {}; J.A1 = P.c; J.lda1 = H_; J.K1 = H_; J.cg1 = 1;
      J.W1 = P.Wv; J.b1 = P.bv; J.out = P.Vbuf + (size_t)slot * BH_; J.N = H_;
      J.m0 = (l >> 2) * 64; J.n0 = (l & 3) * 128; J.doElu = 1;
      gemm_tile(J, tid, As, Bs, scl, shf);
    } else if (bid < 112) {
      if (t > 0) { prepP(P.stP, P.g_post, P.be_post, scl, shf, tid); __syncthreads(); }
      const int ix = bid - 48;
      GJ J = {}; J.A1 = xt; J.lda1 = F_; J.K1 = F_;
      if (t > 0) { J.A2 = P.hv; J.lda2 = H_; J.K2 = H_; J.nrm2 = 1; J.cg2 = 1; }
      J.W1 = P.W_ih; J.W2 = P.W_hh;
      J.b1 = P.b_ih; J.b2 = P.b_ac; J.out = P.pre; J.N = H4_;
      J.m0 = (ix >> 4) * 64; J.n0 = (ix & 15) * 128;
      gemm_tile(J, tid, As, Bs, scl, shf);
    } else if (bid >= 224 && t > 0) {
      prepP(P.stP, P.g_post, P.be_post, scl, shf, tid);
      __syncthreads();
      const int rb0 = (bid - 224) * 8;
      for (int idx = tid; idx < 1024; idx += NTHR) {
        int r = rb0 + (idx >> 7), cc = (idx & 127) * 4;
        f4 hvv = ld_c(P.hv + (size_t)r * H_ + cc);
        f4 v;
        #pragma unroll
        for (int i = 0; i < 4; ++i) v[i] = hvv[i] * scl[cc + i] + shf[cc + i];
        *(f4*)(P.out + (size_t)(t - 1) * BH_ + (size_t)r * H_ + cc) = v;
      }
    }
    gbar(P.arr, P.gen, ++g);

    // =========== P2: Qh = q@Wq + bq (16 blocks) ===========
    if (bid < 16) {
      GJ J = {}; J.A1 = P.q; J.lda1 = H_; J.K1 = H_; J.cg1 = 1;
      J.W1 = P.Wq; J.b1 = P.bq; J.out = P.Qh; J.N = H_;
      J.m0 = (bid >> 2) * 64; J.n0 = (bid & 3) * 128;
      gemm_tile(J, tid, As, Bs, scl, shf);
    }
    gbar(P.arr, P.gen, ++g);

    // =========== P3: attention (1 batch row / block) ===========
    {
      const int b = bid;
      const int nv = (t + 1 < W_) ? t + 1 : W_;
      if (tid < 128) *(f4*)&Qs[tid * 4] = ld_c(P.Qh + (size_t)b * H_ + tid * 4);
      __syncthreads();
      {
        const int p = tid >> 2, l4 = tid & 3;
        const int hh = p >> 4, w = p & 15;
        if (w < nv) {
          const int sl = (t - 1 - w) & 15;
          const float* kp = P.Kbuf + ((size_t)sl * B_ + b) * H_ + hh * 64 + l4 * 16;
          const float* qp = Qs + hh * 64 + l4 * 16;
          float s = 0.f;
          #pragma unroll
          for (int d = 0; d < 16; d += 4) {
            f4 kv = ld_c(kp + d);
            f4 qv = *(const f4*)(qp + d);
            s = fmaf(kv[0], qv[0], fmaf(kv[1], qv[1], fmaf(kv[2], qv[2], fmaf(kv[3], qv[3], s))));
          }
          s += __shfl_xor(s, 1); s += __shfl_xor(s, 2);
          if (l4 == 0) sc_[hh][w] = s * 0.125f;
        }
      }
      __syncthreads();
      if (tid < 8) {
        float mx = -1e30f;
        for (int w = 0; w < nv; ++w) mx = fmaxf(mx, sc_[tid][w]);
        float ss = 0.f;
        for (int w = 0; w < nv; ++w) { float e = expf(sc_[tid][w] - mx); aw_[tid][w] = e; ss += e; }
        float inv = 1.f / ss;
        for (int w = 0; w < nv; ++w) aw_[tid][w] *= inv;
      }
      __syncthreads();
      {
        const int j = tid, hh = j >> 6;
        float o = 0.f;
        for (int w = 0; w < nv; ++w) {
          const int sl = (t - 1 - w) & 15;
          o = fmaf(aw_[hh][w], ldf_c(P.Vbuf + ((size_t)sl * B_ + b) * H_ + j), o);
        }
        stf_c(P.ctx + (size_t)b * H_ + j, o);
      }
    }
    gbar(P.arr, P.gen, ++g);

    // =========== P4: attp = elu(ctx@Wo + bo) + BN partials (16 blocks) ===========
    if (bid < 16) {
      GJ J = {}; J.A1 = P.ctx; J.lda1 = H_; J.K1 = H_; J.cg1 = 1;
      J.W1 = P.Wo; J.b1 = P.bo; J.doElu = 1;
      J.out = P.attp; J.stats = P.stA; J.N = H_;
      J.m0 = (bid >> 2) * 64; J.n0 = (bid & 3) * 128;
      gemm_tile(J, tid, As, Bs, scl, shf);
    }
    gbar(P.arr, P.gen, ++g);

    // =========== P5: pre += BN(attp)@W_ac (64 blocks) ===========
    if (bid < 64) {
      prepA(P.stA, P.g_att, P.be_att, scl, shf, tid);
      __syncthreads();
      GJ J = {}; J.A1 = P.attp; J.lda1 = H_; J.K1 = H_; J.cg1 = 1; J.nrm1 = 1;
      J.W1 = P.W_ac; J.addm = P.pre; J.out = P.pre; J.N = H4_;
      J.m0 = (bid >> 4) * 64; J.n0 = (bid & 15) * 128;
      gemm_tile(J, tid, As, Bs, scl, shf);
    }
    gbar(P.arr, P.gen, ++g);

    // =========== P6: gates + c/hv + BN-post stats (64 blocks) ===========
    if (bid < 64) {
      f4* rS = (f4*)As;
      f4* rQ = (f4*)Bs;
      const int sub = tid & 1, r = tid >> 1;
      const int c4 = bid * 8 + sub * 4;
      const size_t rb = (size_t)r * H4_;
      f4 p0 = ld_c(P.pre + rb + c4);
      f4 pf = ld_c(P.pre + rb + c4 + 512);
      f4 pi = ld_c(P.pre + rb + c4 + 1024);
      f4 po = ld_c(P.pre + rb + c4 + 1536);
      const size_t ci = (size_t)r * H_ + c4;
      f4 cold = ld_c(P.c + ci);
      f4 cn, hvv;
      #pragma unroll
      for (int i = 0; i < 4; ++i) {
        float iv = tanhf(p0[i]);
        float fg = sigf(pf[i]), ig = sigf(pi[i]), og = sigf(po[i]);
        cn[i] = iv * ig + cold[i] * fg;
        hvv[i] = og * eluf(cn[i]);
      }
      st_c(P.c + ci, cn);
      st_c(P.hv + ci, hvv);
      rS[sub * 256 + r] = hvv;
      rQ[sub * 256 + r] = hvv * hvv;
      __syncthreads();
      for (int s2 = 128; s2 > 0; s2 >>= 1) {
        if (r < s2) {
          rS[sub * 256 + r] += rS[sub * 256 + r + s2];
          rQ[sub * 256 + r] += rQ[sub * 256 + r + s2];
        }
        __syncthreads();
      }
      if (r == 0) {
        f4 S = rS[sub * 256], Q2 = rQ[sub * 256];
        #pragma unroll
        for (int i = 0; i < 4; ++i) { stf_c(P.stP + c4 + i, S[i]); stf_c(P.stP + 512 + c4 + i, Q2[i]); }
      }
    }
    gbar(P.arr, P.gen, ++g);
  }

  // =========== final out-copy for t = 127 ===========
  if (bid >= 224) {
    prepP(P.stP, P.g_post, P.be_post, scl, shf, tid);
    __syncthreads();
    const int rb0 = (bid - 224) * 8;
    for (int idx = tid; idx < 1024; idx += NTHR) {
      int r = rb0 + (idx >> 7), cc = (idx & 127) * 4;
      f4 hvv = ld_c(P.hv + (size_t)r * H_ + cc);
      f4 v;
      #pragma unroll
      for (int i = 0; i < 4; ++i) v[i] = hvv[i] * scl[cc + i] + shf[cc + i];
      *(f4*)(P.out + (size_t)127 * BH_ + (size_t)r * H_ + cc) = v;
    }
  }
}

#define SYNC_UINTS (32 + NBLK * FSTRIDE)   // gen line + 256 padded flags

__global__ __launch_bounds__(256) void pinit(float* c, unsigned* sync) {
  const int i = blockIdx.x * 256 + threadIdx.x;
  if (i < BH_) c[i] = 0.f;
  if (i < SYNC_UINTS) sync[i] = 0u;
}

extern "C" void kernel_launch(void* const* d_in, const int* in_sizes, int n_in,
                              void* d_out, int out_size, void* d_ws, size_t ws_size,
                              hipStream_t stream) {
  Params P;
  P.x      = (const float*)d_in[0];
  P.W_ih   = (const float*)d_in[1];
  P.b_ih   = (const float*)d_in[2];
  P.W_hh   = (const float*)d_in[3];
  P.Wq_in  = (const float*)d_in[4];
  P.bq_in  = (const float*)d_in[5];
  P.Wq     = (const float*)d_in[6];
  P.bq     = (const float*)d_in[7];
  P.Wk     = (const float*)d_in[8];
  P.bk     = (const float*)d_in[9];
  P.Wv     = (const float*)d_in[10];
  P.bv     = (const float*)d_in[11];
  P.Wo     = (const float*)d_in[12];
  P.bo     = (const float*)d_in[13];
  P.W_ac   = (const float*)d_in[14];
  P.b_ac   = (const float*)d_in[15];
  P.g_att  = (const float*)d_in[16];
  P.be_att = (const float*)d_in[17];
  P.g_post = (const float*)d_in[18];
  P.be_post= (const float*)d_in[19];
  P.out    = (float*)d_out;

  unsigned* sync = (unsigned*)d_ws;
  P.gen = sync;                    // own 128B line
  P.arr = sync + 32;               // 256 flags, 128B stride
  float* fb = (float*)d_ws + SYNC_UINTS;
  P.c    = fb;                 fb += BH_;
  P.q    = fb;                 fb += BH_;
  P.Qh   = fb;                 fb += BH_;
  P.ctx  = fb;                 fb += BH_;
  P.attp = fb;                 fb += BH_;
  P.hv   = fb;                 fb += BH_;
  P.pre  = fb;                 fb += (size_t)B_ * H4_;
  P.Kbuf = fb;                 fb += (size_t)W_ * BH_;
  P.Vbuf = fb;                 fb += (size_t)W_ * BH_;
  P.stA  = fb;                 fb += 4096;
  P.stP  = fb;                 fb += 1024;

  pinit<<<(BH_ + 255) / 256, 256, 0, stream>>>(P.c, sync);
  larnn<<<NBLK, NTHR, 0, stream>>>(P);
}

// Round 14
// 17476.904 us; speedup vs baseline: 1.9246x; 1.9246x over previous
//
#include <hip/hip_runtime.h>
#include <math.h>

// ============================================================================
// LARNN forward, MI355X — persistent kernel, fence-free sc1 (round-11 base,
// verified 16.06 ms). ALL-F32 (bf16 diverges — chaotic recurrence). Det. BN.
// Round 14 = round 11 EXACTLY, except: P2 (Qh GEMM phase) deleted; each
// attention block computes its Qh row as a fused GEMV (q via same-addr sc1
// broadcast loads, Wq via coalesced plain loads, L2-resident). 5 barriers/step.
// r13 lesson: latency-bound phases need MORE blocks, not bigger tiles.
// ============================================================================

#define T_  128
#define B_  256
#define F_  128
#define H_  512
#define W_  16
#define H4_ 2048
#define EPS_ 1e-5f
#define BH_ (B_*H_)
#define NBLK 256
#define NTHR 512
#define FSTRIDE 32   // uints per flag (128B line)

typedef __attribute__((ext_vector_type(4))) float f4;
typedef __attribute__((ext_vector_type(2))) float f2;
typedef unsigned long long u64;

__device__ __forceinline__ float eluf(float x){ return x > 0.f ? x : expf(x) - 1.f; }
__device__ __forceinline__ float sigf(float x){ return 1.f / (1.f + expf(-x)); }

// ---- LLC-coherent (sc1) relaxed accessors: no cache maintenance emitted ----
__device__ __forceinline__ f4 ld_c(const float* p) {
  union { f4 v; u64 q[2]; } u;
  u.q[0] = __hip_atomic_load((const u64*)p,     __ATOMIC_RELAXED, __HIP_MEMORY_SCOPE_AGENT);
  u.q[1] = __hip_atomic_load((const u64*)p + 1, __ATOMIC_RELAXED, __HIP_MEMORY_SCOPE_AGENT);
  return u.v;
}
__device__ __forceinline__ void st_c(float* p, f4 v) {
  union { f4 v; u64 q[2]; } u; u.v = v;
  __hip_atomic_store((u64*)p,     u.q[0], __ATOMIC_RELAXED, __HIP_MEMORY_SCOPE_AGENT);
  __hip_atomic_store((u64*)p + 1, u.q[1], __ATOMIC_RELAXED, __HIP_MEMORY_SCOPE_AGENT);
}
__device__ __forceinline__ float ldf_c(const float* p) {
  unsigned u = __hip_atomic_load((const unsigned*)p, __ATOMIC_RELAXED, __HIP_MEMORY_SCOPE_AGENT);
  return __uint_as_float(u);
}
__device__ __forceinline__ void stf_c(float* p, float v) {
  __hip_atomic_store((unsigned*)p, __float_as_uint(v), __ATOMIC_RELAXED, __HIP_MEMORY_SCOPE_AGENT);
}

struct Params {
  const float *x, *W_ih, *b_ih, *W_hh, *Wq_in, *bq_in, *Wq, *bq, *Wk, *bk,
              *Wv, *bv, *Wo, *bo, *W_ac, *b_ac, *g_att, *be_att, *g_post, *be_post;
  float *out, *c, *q, *Qh, *ctx, *attp, *hv, *pre, *Kbuf, *Vbuf, *stA, *stP;
  unsigned *gen, *arr;
};

// Round-7/11 barrier: flag store + block-0 parallel aggregation + gen release.
__device__ __forceinline__ void gbar(unsigned* arr, unsigned* gen, unsigned g) {
  asm volatile("s_waitcnt vmcnt(0) lgkmcnt(0)" ::: "memory");
  __syncthreads();
  const int tid = threadIdx.x;
  if (tid == 0)
    __hip_atomic_store(&arr[blockIdx.x * FSTRIDE], g, __ATOMIC_RELAXED, __HIP_MEMORY_SCOPE_AGENT);
  if (blockIdx.x == 0) {
    if (tid < NBLK) {
      while (__hip_atomic_load(&arr[tid * FSTRIDE], __ATOMIC_RELAXED, __HIP_MEMORY_SCOPE_AGENT) < g)
        __builtin_amdgcn_s_sleep(1);
    }
    __syncthreads();
    if (tid == 0)
      __hip_atomic_store(gen, g, __ATOMIC_RELAXED, __HIP_MEMORY_SCOPE_AGENT);
  } else {
    if (tid == 0) {
      while (__hip_atomic_load(gen, __ATOMIC_RELAXED, __HIP_MEMORY_SCOPE_AGENT) < g)
        __builtin_amdgcn_s_sleep(1);
    }
  }
  __syncthreads();
}

// BN scale/shift from single-partial stats stP[2][512] (gates output).
__device__ __forceinline__ void prepP(const float* stP, const float* gn, const float* be,
                                      float* scl, float* shf, int tid) {
  if (tid < H_) {
    float S  = ldf_c(stP + tid);
    float S2 = ldf_c(stP + H_ + tid);
    float mu  = S * (1.f / B_);
    float var = S2 * (1.f / B_) - mu * mu;
    float sc  = rsqrtf(var + EPS_) * gn[tid];
    scl[tid] = sc; shf[tid] = be[tid] - mu * sc;
  }
}

// BN scale/shift from 4-way partial stats stA[4][2][512] (Wo GEMM output).
__device__ __forceinline__ void prepA(const float* stA, const float* gn, const float* be,
                                      float* scl, float* shf, int tid) {
  if (tid < H_) {
    float S  = ldf_c(stA + tid) + ldf_c(stA + 1024 + tid) + ldf_c(stA + 2048 + tid) + ldf_c(stA + 3072 + tid);
    float S2 = ldf_c(stA + 512 + tid) + ldf_c(stA + 1536 + tid) + ldf_c(stA + 2560 + tid) + ldf_c(stA + 3584 + tid);
    float mu  = S * (1.f / B_);
    float var = S2 * (1.f / B_) - mu * mu;
    float sc  = rsqrtf(var + EPS_) * gn[tid];
    scl[tid] = sc; shf[tid] = be[tid] - mu * sc;
  }
}

// ---------------------------------------------------------------------------
// 64x64 output tile, K-concat of up to 2 segments, 512 threads, 2x4 microtile.
// LDS double-buffered; ONE sync per 32-k slab. Prefetch: A depth-2, B depth-1,
// all as NAMED f4 values (register arrays across the K-loop spill — rule #20).
// (UNCHANGED from round 11 — verified no-spill, 128 VGPR.)
// ---------------------------------------------------------------------------
struct GJ {
  const float* A1; int lda1; int K1; int nrm1; int cg1;
  const float* A2; int lda2; int K2; int nrm2; int cg2;
  const float* W1; const float* W2;    // [K][N] row-major, stride N (plain)
  const float* b1; const float* b2; const float* addm;
  float* out; float* stats;
  int N; int m0; int n0; int doElu;
};

__device__ void gemm_tile(const GJ& J, int tid,
                          float (*As)[64][36], float (*Bs)[32][68],
                          const float* scl, const float* shf) {
  const int arow = tid >> 3, akq = (tid & 7) * 4;
  const int bkk = tid >> 4, bnn = (tid & 15) * 4;
  const int ty = tid >> 4, tx = tid & 15;

  float acc[2][4] = {{0.f,0.f,0.f,0.f},{0.f,0.f,0.f,0.f}};

  f4 am0 = {0.f,0.f,0.f,0.f}, am1 = {0.f,0.f,0.f,0.f};
  if (J.addm) {
    am0 = ld_c(J.addm + (size_t)(J.m0 + ty * 2)     * J.N + J.n0 + tx * 4);
    am1 = ld_c(J.addm + (size_t)(J.m0 + ty * 2 + 1) * J.N + J.n0 + tx * 4);
  }

  int buf = 0;
  for (int s = 0; s < 2; ++s) {
    const float* A = s ? J.A2 : J.A1;
    if (!A) break;
    const float* Wp  = s ? J.W2 : J.W1;
    const int K      = s ? J.K2 : J.K1;
    const int lda    = s ? J.lda2 : J.lda1;
    const int nrm    = s ? J.nrm2 : J.nrm1;
    const int cg     = s ? J.cg2 : J.cg1;
    const int nsl    = K >> 5;

    const float* aBase = A + (size_t)(J.m0 + arow) * lda + akq;
    const float* wBase = Wp + (size_t)bkk * J.N + J.n0 + bnn;
    const size_t wSlab = (size_t)32 * J.N;

    // prologue: named-value prefetch (depth 2 for A, 1 for B)
    f4 aN1 = cg ? ld_c(aBase) : *(const f4*)aBase;
    f4 aN2 = (nsl > 1) ? (cg ? ld_c(aBase + 32) : *(const f4*)(aBase + 32)) : aN1;
    f4 bN1 = *(const f4*)wBase;

    for (int sl = 0; sl < nsl; ++sl) {
      f4 aCur = aN1; aN1 = aN2;
      f4 bCur = bN1;
      if (sl + 2 < nsl) {
        const float* ap = aBase + (size_t)(sl + 2) * 32;
        aN2 = cg ? ld_c(ap) : *(const f4*)ap;
      }
      if (sl + 1 < nsl) bN1 = *(const f4*)(wBase + (size_t)(sl + 1) * wSlab);
      if (nrm) {
        #pragma unroll
        for (int i = 0; i < 4; ++i) {
          int gk = sl * 32 + akq + i;
          aCur[i] = aCur[i] * scl[gk] + shf[gk];
        }
      }
      *(f4*)&As[buf][arow][akq] = aCur;
      *(f4*)&Bs[buf][bkk][bnn] = bCur;
      __syncthreads();
      #pragma unroll
      for (int k = 0; k < 32; k += 2) {
        f2 a0 = *(const f2*)&As[buf][ty * 2][k];
        f2 a1 = *(const f2*)&As[buf][ty * 2 + 1][k];
        f4 b0 = *(const f4*)&Bs[buf][k][tx * 4];
        f4 b1 = *(const f4*)&Bs[buf][k + 1][tx * 4];
        #pragma unroll
        for (int j = 0; j < 4; ++j) {
          acc[0][j] = fmaf(a0[0], b0[j], acc[0][j]);
          acc[0][j] = fmaf(a0[1], b1[j], acc[0][j]);
          acc[1][j] = fmaf(a1[0], b0[j], acc[1][j]);
          acc[1][j] = fmaf(a1[1], b1[j], acc[1][j]);
        }
      }
      buf ^= 1;
    }
  }

  const int r0 = J.m0 + ty * 2, c0 = J.n0 + tx * 4;
  f4 bias = {0.f, 0.f, 0.f, 0.f};
  if (J.b1) bias += *(const f4*)(J.b1 + c0);
  if (J.b2) bias += *(const f4*)(J.b2 + c0);
  f4 v0, v1;
  #pragma unroll
  for (int j = 0; j < 4; ++j) { v0[j] = acc[0][j] + bias[j]; v1[j] = acc[1][j] + bias[j]; }
  if (J.addm) { v0 += am0; v1 += am1; }
  if (J.doElu) {
    #pragma unroll
    for (int j = 0; j < 4; ++j) { v0[j] = eluf(v0[j]); v1[j] = eluf(v1[j]); }
  }
  st_c(J.out + (size_t)r0 * J.N + c0, v0);
  st_c(J.out + (size_t)(r0 + 1) * J.N + c0, v1);

  if (J.stats) {   // deterministic per-64-row-tile column partials
    float* Af = (float*)As;
    float* Bf = (float*)Bs;
    __syncthreads();
    #pragma unroll
    for (int j = 0; j < 4; ++j) {
      Af[ty * 64 + tx * 4 + j] = v0[j] + v1[j];
      Bf[ty * 64 + tx * 4 + j] = v0[j] * v0[j] + v1[j] * v1[j];
    }
    __syncthreads();
    if (tid < 64) {
      float S = 0.f, S2 = 0.f;
      #pragma unroll
      for (int y = 0; y < 32; ++y) { S += Af[y * 64 + tid]; S2 += Bf[y * 64 + tid]; }
      const int tm = J.m0 >> 6;
      stf_c(J.stats + tm * 1024 + J.n0 + tid, S);
      stf_c(J.stats + tm * 1024 + 512 + J.n0 + tid, S2);
    }
  }
}

__global__ __launch_bounds__(NTHR, 1) void larnn(Params P) {
  __shared__ float As[2][64][36];
  __shared__ float Bs[2][32][68];
  __shared__ float scl[H_], shf[H_];
  __shared__ float Qs[H_];
  __shared__ float sc_[8][16], aw_[8][16];

  const int bid = blockIdx.x, tid = threadIdx.x;
  unsigned g = 0;

  for (int t = 0; t < T_; ++t) {
    const float* xt = P.x + (size_t)t * B_ * F_;
    const int slot = (t - 1) & 15;

    // =========== P1: q | K-ring | V-ring | preA | out[t-1] ===========
    if (bid < 32) {
      if (t > 0) { prepP(P.stP, P.g_post, P.be_post, scl, shf, tid); __syncthreads(); }
      GJ J = {}; J.A1 = xt; J.lda1 = F_; J.K1 = F_;
      if (t > 0) { J.A2 = P.hv; J.lda2 = H_; J.K2 = H_; J.nrm2 = 1; J.cg2 = 1; }
      J.W1 = P.Wq_in; J.W2 = P.Wq_in + (size_t)F_ * H_;
      J.b1 = P.bq_in; J.out = P.q; J.N = H_;
      J.m0 = (bid >> 3) * 64; J.n0 = (bid & 7) * 64; J.doElu = 1;
      gemm_tile(J, tid, As, Bs, scl, shf);
    } else if (bid < 64) {
      int l = bid - 32;
      GJ J = {}; J.A1 = P.c; J.lda1 = H_; J.K1 = H_; J.cg1 = 1;
      J.W1 = P.Wk; J.b1 = P.bk; J.out = P.Kbuf + (size_t)slot * BH_; J.N = H_;
      J.m0 = (l >> 3) * 64; J.n0 = (l & 7) * 64; J.doElu = 1;
      gemm_tile(J, tid, As, Bs, scl, shf);
    } else if (bid < 96) {
      int l = bid - 64;
      GJ J = {}; J.A1 = P.c; J.lda1 = H_; J.K1 = H_; J.cg1 = 1;
      J.W1 = P.Wv; J.b1 = P.bv; J.out = P.Vbuf + (size_t)slot * BH_; J.N = H_;
      J.m0 = (l >> 3) * 64; J.n0 = (l & 7) * 64; J.doElu = 1;
      gemm_tile(J, tid, As, Bs, scl, shf);
    } else if (bid < 224) {
      if (t > 0) { prepP(P.stP, P.g_post, P.be_post, scl, shf, tid); __syncthreads(); }
      const int ix = bid - 96;
      GJ J = {}; J.A1 = xt; J.lda1 = F_; J.K1 = F_;
      if (t > 0) { J.A2 = P.hv; J.lda2 = H_; J.K2 = H_; J.nrm2 = 1; J.cg2 = 1; }
      J.W1 = P.W_ih; J.W2 = P.W_hh;
      J.b1 = P.b_ih; J.b2 = P.b_ac; J.out = P.pre; J.N = H4_;
      J.m0 = (ix >> 5) * 64; J.n0 = (ix & 31) * 64;
      gemm_tile(J, tid, As, Bs, scl, shf);
    } else if (t > 0) {
      prepP(P.stP, P.g_post, P.be_post, scl, shf, tid);
      __syncthreads();
      const int rb0 = (bid - 224) * 8;
      for (int idx = tid; idx < 1024; idx += NTHR) {
        int r = rb0 + (idx >> 7), cc = (idx & 127) * 4;
        f4 hvv = ld_c(P.hv + (size_t)r * H_ + cc);
        f4 v;
        #pragma unroll
        for (int i = 0; i < 4; ++i) v[i] = hvv[i] * scl[cc + i] + shf[cc + i];
        *(f4*)(P.out + (size_t)(t - 1) * BH_ + (size_t)r * H_ + cc) = v;
      }
    }
    gbar(P.arr, P.gen, ++g);

    // =========== P2: fused Qh-GEMV + attention (1 batch row / block) ===========
    {
      const int b = bid;
      const int nv = (t + 1 < W_) ? t + 1 : W_;
      // Qh GEMV: thread n computes Qh[b][n] -> Qs[n].
      // q read as same-addr sc1 broadcast f4; Wq coalesced plain loads (L2-hot).
      {
        float acc = P.bq[tid];
        const float* wcol = P.Wq + tid;
        const float* qrow = P.q + (size_t)b * H_;
        #pragma unroll 2
        for (int k4 = 0; k4 < 128; ++k4) {
          f4 qv = ld_c(qrow + k4 * 4);
          const float* wp = wcol + (size_t)(k4 * 4) * H_;
          acc = fmaf(qv[0], wp[0],
                fmaf(qv[1], wp[(size_t)H_],
                fmaf(qv[2], wp[(size_t)2 * H_],
                fmaf(qv[3], wp[(size_t)3 * H_], acc))));
        }
        Qs[tid] = acc;
      }
      __syncthreads();
      {
        const int p = tid >> 2, l4 = tid & 3;
        const int hh = p >> 4, w = p & 15;
        if (w < nv) {
          const int sl = (t - 1 - w) & 15;
          const float* kp = P.Kbuf + ((size_t)sl * B_ + b) * H_ + hh * 64 + l4 * 16;
          const float* qp = Qs + hh * 64 + l4 * 16;
          float s = 0.f;
          #pragma unroll
          for (int d = 0; d < 16; d += 4) {
            f4 kv = ld_c(kp + d);
            f4 qv = *(const f4*)(qp + d);
            s = fmaf(kv[0], qv[0], fmaf(kv[1], qv[1], fmaf(kv[2], qv[2], fmaf(kv[3], qv[3], s))));
          }
          s += __shfl_xor(s, 1); s += __shfl_xor(s, 2);
          if (l4 == 0) sc_[hh][w] = s * 0.125f;
        }
      }
      __syncthreads();
      if (tid < 8) {
        float mx = -1e30f;
        for (int w = 0; w < nv; ++w) mx = fmaxf(mx, sc_[tid][w]);
        float ss = 0.f;
        for (int w = 0; w < nv; ++w) { float e = expf(sc_[tid][w] - mx); aw_[tid][w] = e; ss += e; }
        float inv = 1.f / ss;
        for (int w = 0; w < nv; ++w) aw_[tid][w] *= inv;
      }
      __syncthreads();
      {
        const int j = tid, hh = j >> 6;
        float o = 0.f;
        for (int w = 0; w < nv; ++w) {
          const int sl = (t - 1 - w) & 15;
          o = fmaf(aw_[hh][w], ldf_c(P.Vbuf + ((size_t)sl * B_ + b) * H_ + j), o);
        }
        stf_c(P.ctx + (size_t)b * H_ + j, o);
      }
    }
    gbar(P.arr, P.gen, ++g);

    // =========== P3: attp = elu(ctx@Wo + bo) + BN partials ===========
    if (bid < 32) {
      GJ J = {}; J.A1 = P.ctx; J.lda1 = H_; J.K1 = H_; J.cg1 = 1;
      J.W1 = P.Wo; J.b1 = P.bo; J.doElu = 1;
      J.out = P.attp; J.stats = P.stA; J.N = H_;
      J.m0 = (bid >> 3) * 64; J.n0 = (bid & 7) * 64;
      gemm_tile(J, tid, As, Bs, scl, shf);
    }
    gbar(P.arr, P.gen, ++g);

    // =========== P4: pre += BN(attp)@W_ac ===========
    if (bid < 128) {
      prepA(P.stA, P.g_att, P.be_att, scl, shf, tid);
      __syncthreads();
      GJ J = {}; J.A1 = P.attp; J.lda1 = H_; J.K1 = H_; J.cg1 = 1; J.nrm1 = 1;
      J.W1 = P.W_ac; J.addm = P.pre; J.out = P.pre; J.N = H4_;
      J.m0 = (bid >> 5) * 64; J.n0 = (bid & 31) * 64;
      gemm_tile(J, tid, As, Bs, scl, shf);
    }
    gbar(P.arr, P.gen, ++g);

    // =========== P5: gates + c/hv + BN-post stats ===========
    if (bid < 64) {
      f4* rS = (f4*)As;
      f4* rQ = (f4*)Bs;
      const int sub = tid & 1, r = tid >> 1;
      const int c4 = bid * 8 + sub * 4;
      const size_t rb = (size_t)r * H4_;
      f4 p0 = ld_c(P.pre + rb + c4);
      f4 pf = ld_c(P.pre + rb + c4 + 512);
      f4 pi = ld_c(P.pre + rb + c4 + 1024);
      f4 po = ld_c(P.pre + rb + c4 + 1536);
      const size_t ci = (size_t)r * H_ + c4;
      f4 cold = ld_c(P.c + ci);
      f4 cn, hvv;
      #pragma unroll
      for (int i = 0; i < 4; ++i) {
        float iv = tanhf(p0[i]);
        float fg = sigf(pf[i]), ig = sigf(pi[i]), og = sigf(po[i]);
        cn[i] = iv * ig + cold[i] * fg;
        hvv[i] = og * eluf(cn[i]);
      }
      st_c(P.c + ci, cn);
      st_c(P.hv + ci, hvv);
      rS[sub * 256 + r] = hvv;
      rQ[sub * 256 + r] = hvv * hvv;
      __syncthreads();
      for (int s2 = 128; s2 > 0; s2 >>= 1) {
        if (r < s2) {
          rS[sub * 256 + r] += rS[sub * 256 + r + s2];
          rQ[sub * 256 + r] += rQ[sub * 256 + r + s2];
        }
        __syncthreads();
      }
      if (r == 0) {
        f4 S = rS[sub * 256], Q2 = rQ[sub * 256];
        #pragma unroll
        for (int i = 0; i < 4; ++i) { stf_c(P.stP + c4 + i, S[i]); stf_c(P.stP + 512 + c4 + i, Q2[i]); }
      }
    }
    gbar(P.arr, P.gen, ++g);
  }

  // =========== final out-copy for t = 127 ===========
  if (bid >= 224) {
    prepP(P.stP, P.g_post, P.be_post, scl, shf, tid);
    __syncthreads();
    const int rb0 = (bid - 224) * 8;
    for (int idx = tid; idx < 1024; idx += NTHR) {
      int r = rb0 + (idx >> 7), cc = (idx & 127) * 4;
      f4 hvv = ld_c(P.hv + (size_t)r * H_ + cc);
      f4 v;
      #pragma unroll
      for (int i = 0; i < 4; ++i) v[i] = hvv[i] * scl[cc + i] + shf[cc + i];
      *(f4*)(P.out + (size_t)127 * BH_ + (size_t)r * H_ + cc) = v;
    }
  }
}

#define SYNC_UINTS (32 + NBLK * FSTRIDE)   // gen line + 256 padded flags

__global__ __launch_bounds__(256) void pinit(float* c, unsigned* sync) {
  const int i = blockIdx.x * 256 + threadIdx.x;
  if (i < BH_) c[i] = 0.f;
  if (i < SYNC_UINTS) sync[i] = 0u;
}

extern "C" void kernel_launch(void* const* d_in, const int* in_sizes, int n_in,
                              void* d_out, int out_size, void* d_ws, size_t ws_size,
                              hipStream_t stream) {
  Params P;
  P.x      = (const float*)d_in[0];
  P.W_ih   = (const float*)d_in[1];
  P.b_ih   = (const float*)d_in[2];
  P.W_hh   = (const float*)d_in[3];
  P.Wq_in  = (const float*)d_in[4];
  P.bq_in  = (const float*)d_in[5];
  P.Wq     = (const float*)d_in[6];
  P.bq     = (const float*)d_in[7];
  P.Wk     = (const float*)d_in[8];
  P.bk     = (const float*)d_in[9];
  P.Wv     = (const float*)d_in[10];
  P.bv     = (const float*)d_in[11];
  P.Wo     = (const float*)d_in[12];
  P.bo     = (const float*)d_in[13];
  P.W_ac   = (const float*)d_in[14];
  P.b_ac   = (const float*)d_in[15];
  P.g_att  = (const float*)d_in[16];
  P.be_att = (const float*)d_in[17];
  P.g_post = (const float*)d_in[18];
  P.be_post= (const float*)d_in[19];
  P.out    = (float*)d_out;

  unsigned* sync = (unsigned*)d_ws;
  P.gen = sync;                    // own 128B line
  P.arr = sync + 32;               // 256 flags, 128B stride
  float* fb = (float*)d_ws + SYNC_UINTS;
  P.c    = fb;                 fb += BH_;
  P.q    = fb;                 fb += BH_;
  P.Qh   = fb;                 fb += BH_;
  P.ctx  = fb;                 fb += BH_;
  P.attp = fb;                 fb += BH_;
  P.hv   = fb;                 fb += BH_;
  P.pre  = fb;                 fb += (size_t)B_ * H4_;
  P.Kbuf = fb;                 fb += (size_t)W_ * BH_;
  P.Vbuf = fb;                 fb += (size_t)W_ * BH_;
  P.stA  = fb;                 fb += 4096;
  P.stP  = fb;                 fb += 1024;

  pinit<<<(BH_ + 255) / 256, 256, 0, stream>>>(P.c, sync);
  larnn<<<NBLK, NTHR, 0, stream>>>(P);
}

// Round 15
// 16705.533 us; speedup vs baseline: 2.0135x; 1.0462x over previous
//
#include <hip/hip_runtime.h>
#include <math.h>

// ============================================================================
// LARNN forward, MI355X — persistent kernel, fence-free sc1 (round-11 base,
// verified 16.06 ms). ALL-F32 (bf16 diverges — chaotic recurrence). Det. BN.
// Round 15 = round 11 EXACTLY, except the GEMM inner k-loop is explicitly
// register-pipelined depth-2 (named SSA values, full unroll, no arrays):
// r11's phases ran ~2.3x above instruction-issue floor — LDS-read latency
// (~120cyc) stall at 2 waves/SIMD. Loads for k+4 now issue before k's FMAs.
// (r14's fused GEMV reverted: serialized sc1 broadcast chain cost 23us/step.)
// ============================================================================

#define T_  128
#define B_  256
#define F_  128
#define H_  512
#define W_  16
#define H4_ 2048
#define EPS_ 1e-5f
#define BH_ (B_*H_)
#define NBLK 256
#define NTHR 512
#define FSTRIDE 32   // uints per flag (128B line)

typedef __attribute__((ext_vector_type(4))) float f4;
typedef __attribute__((ext_vector_type(2))) float f2;
typedef unsigned long long u64;

__device__ __forceinline__ float eluf(float x){ return x > 0.f ? x : expf(x) - 1.f; }
__device__ __forceinline__ float sigf(float x){ return 1.f / (1.f + expf(-x)); }

// ---- LLC-coherent (sc1) relaxed accessors: no cache maintenance emitted ----
__device__ __forceinline__ f4 ld_c(const float* p) {
  union { f4 v; u64 q[2]; } u;
  u.q[0] = __hip_atomic_load((const u64*)p,     __ATOMIC_RELAXED, __HIP_MEMORY_SCOPE_AGENT);
  u.q[1] = __hip_atomic_load((const u64*)p + 1, __ATOMIC_RELAXED, __HIP_MEMORY_SCOPE_AGENT);
  return u.v;
}
__device__ __forceinline__ void st_c(float* p, f4 v) {
  union { f4 v; u64 q[2]; } u; u.v = v;
  __hip_atomic_store((u64*)p,     u.q[0], __ATOMIC_RELAXED, __HIP_MEMORY_SCOPE_AGENT);
  __hip_atomic_store((u64*)p + 1, u.q[1], __ATOMIC_RELAXED, __HIP_MEMORY_SCOPE_AGENT);
}
__device__ __forceinline__ float ldf_c(const float* p) {
  unsigned u = __hip_atomic_load((const unsigned*)p, __ATOMIC_RELAXED, __HIP_MEMORY_SCOPE_AGENT);
  return __uint_as_float(u);
}
__device__ __forceinline__ void stf_c(float* p, float v) {
  __hip_atomic_store((unsigned*)p, __float_as_uint(v), __ATOMIC_RELAXED, __HIP_MEMORY_SCOPE_AGENT);
}

struct Params {
  const float *x, *W_ih, *b_ih, *W_hh, *Wq_in, *bq_in, *Wq, *bq, *Wk, *bk,
              *Wv, *bv, *Wo, *bo, *W_ac, *b_ac, *g_att, *be_att, *g_post, *be_post;
  float *out, *c, *q, *Qh, *ctx, *attp, *hv, *pre, *Kbuf, *Vbuf, *stA, *stP;
  unsigned *gen, *arr;
};

// Round-7/11 barrier: flag store + block-0 parallel aggregation + gen release.
__device__ __forceinline__ void gbar(unsigned* arr, unsigned* gen, unsigned g) {
  asm volatile("s_waitcnt vmcnt(0) lgkmcnt(0)" ::: "memory");
  __syncthreads();
  const int tid = threadIdx.x;
  if (tid == 0)
    __hip_atomic_store(&arr[blockIdx.x * FSTRIDE], g, __ATOMIC_RELAXED, __HIP_MEMORY_SCOPE_AGENT);
  if (blockIdx.x == 0) {
    if (tid < NBLK) {
      while (__hip_atomic_load(&arr[tid * FSTRIDE], __ATOMIC_RELAXED, __HIP_MEMORY_SCOPE_AGENT) < g)
        __builtin_amdgcn_s_sleep(1);
    }
    __syncthreads();
    if (tid == 0)
      __hip_atomic_store(gen, g, __ATOMIC_RELAXED, __HIP_MEMORY_SCOPE_AGENT);
  } else {
    if (tid == 0) {
      while (__hip_atomic_load(gen, __ATOMIC_RELAXED, __HIP_MEMORY_SCOPE_AGENT) < g)
        __builtin_amdgcn_s_sleep(1);
    }
  }
  __syncthreads();
}

// BN scale/shift from single-partial stats stP[2][512] (gates output).
__device__ __forceinline__ void prepP(const float* stP, const float* gn, const float* be,
                                      float* scl, float* shf, int tid) {
  if (tid < H_) {
    float S  = ldf_c(stP + tid);
    float S2 = ldf_c(stP + H_ + tid);
    float mu  = S * (1.f / B_);
    float var = S2 * (1.f / B_) - mu * mu;
    float sc  = rsqrtf(var + EPS_) * gn[tid];
    scl[tid] = sc; shf[tid] = be[tid] - mu * sc;
  }
}

// BN scale/shift from 4-way partial stats stA[4][2][512] (Wo GEMM output).
__device__ __forceinline__ void prepA(const float* stA, const float* gn, const float* be,
                                      float* scl, float* shf, int tid) {
  if (tid < H_) {
    float S  = ldf_c(stA + tid) + ldf_c(stA + 1024 + tid) + ldf_c(stA + 2048 + tid) + ldf_c(stA + 3072 + tid);
    float S2 = ldf_c(stA + 512 + tid) + ldf_c(stA + 1536 + tid) + ldf_c(stA + 2560 + tid) + ldf_c(stA + 3584 + tid);
    float mu  = S * (1.f / B_);
    float var = S2 * (1.f / B_) - mu * mu;
    float sc  = rsqrtf(var + EPS_) * gn[tid];
    scl[tid] = sc; shf[tid] = be[tid] - mu * sc;
  }
}

// ---------------------------------------------------------------------------
// 64x64 output tile, K-concat of up to 2 segments, 512 threads, 2x4 microtile.
// LDS double-buffered; ONE sync per 32-k slab. Staging prefetch: A depth-2,
// B depth-1, named f4 values. Inner k-loop: explicit depth-2 register
// pipeline (k+4's LDS loads issue before k's FMAs) — all named SSA values.
// ---------------------------------------------------------------------------
struct GJ {
  const float* A1; int lda1; int K1; int nrm1; int cg1;
  const float* A2; int lda2; int K2; int nrm2; int cg2;
  const float* W1; const float* W2;    // [K][N] row-major, stride N (plain)
  const float* b1; const float* b2; const float* addm;
  float* out; float* stats;
  int N; int m0; int n0; int doElu;
};

__device__ void gemm_tile(const GJ& J, int tid,
                          float (*As)[64][36], float (*Bs)[32][68],
                          const float* scl, const float* shf) {
  const int arow = tid >> 3, akq = (tid & 7) * 4;
  const int bkk = tid >> 4, bnn = (tid & 15) * 4;
  const int ty = tid >> 4, tx = tid & 15;

  float acc[2][4] = {{0.f,0.f,0.f,0.f},{0.f,0.f,0.f,0.f}};

  f4 am0 = {0.f,0.f,0.f,0.f}, am1 = {0.f,0.f,0.f,0.f};
  if (J.addm) {
    am0 = ld_c(J.addm + (size_t)(J.m0 + ty * 2)     * J.N + J.n0 + tx * 4);
    am1 = ld_c(J.addm + (size_t)(J.m0 + ty * 2 + 1) * J.N + J.n0 + tx * 4);
  }

  int buf = 0;
  for (int s = 0; s < 2; ++s) {
    const float* A = s ? J.A2 : J.A1;
    if (!A) break;
    const float* Wp  = s ? J.W2 : J.W1;
    const int K      = s ? J.K2 : J.K1;
    const int lda    = s ? J.lda2 : J.lda1;
    const int nrm    = s ? J.nrm2 : J.nrm1;
    const int cg     = s ? J.cg2 : J.cg1;
    const int nsl    = K >> 5;

    const float* aBase = A + (size_t)(J.m0 + arow) * lda + akq;
    const float* wBase = Wp + (size_t)bkk * J.N + J.n0 + bnn;
    const size_t wSlab = (size_t)32 * J.N;

    // staging prologue: named-value prefetch (depth 2 for A, 1 for B)
    f4 aN1 = cg ? ld_c(aBase) : *(const f4*)aBase;
    f4 aN2 = (nsl > 1) ? (cg ? ld_c(aBase + 32) : *(const f4*)(aBase + 32)) : aN1;
    f4 bN1 = *(const f4*)wBase;

    for (int sl = 0; sl < nsl; ++sl) {
      f4 aCur = aN1; aN1 = aN2;
      f4 bCur = bN1;
      if (sl + 2 < nsl) {
        const float* ap = aBase + (size_t)(sl + 2) * 32;
        aN2 = cg ? ld_c(ap) : *(const f4*)ap;
      }
      if (sl + 1 < nsl) bN1 = *(const f4*)(wBase + (size_t)(sl + 1) * wSlab);
      if (nrm) {
        #pragma unroll
        for (int i = 0; i < 4; ++i) {
          int gk = sl * 32 + akq + i;
          aCur[i] = aCur[i] * scl[gk] + shf[gk];
        }
      }
      *(f4*)&As[buf][arow][akq] = aCur;
      *(f4*)&Bs[buf][bkk][bnn] = bCur;
      __syncthreads();

      // ---- inner k-loop: depth-2 register pipeline, named SSA values ----
      f2 a0_0 = *(const f2*)&As[buf][ty * 2][0];
      f2 a1_0 = *(const f2*)&As[buf][ty * 2 + 1][0];
      f4 b0_0 = *(const f4*)&Bs[buf][0][tx * 4];
      f4 b1_0 = *(const f4*)&Bs[buf][1][tx * 4];
      f2 a0_1 = *(const f2*)&As[buf][ty * 2][2];
      f2 a1_1 = *(const f2*)&As[buf][ty * 2 + 1][2];
      f4 b0_1 = *(const f4*)&Bs[buf][2][tx * 4];
      f4 b1_1 = *(const f4*)&Bs[buf][3][tx * 4];
      #pragma unroll
      for (int kk = 0; kk < 16; ++kk) {
        f2 a0_2, a1_2; f4 b0_2, b1_2;
        if (kk < 14) {
          const int kn = 2 * kk + 4;
          a0_2 = *(const f2*)&As[buf][ty * 2][kn];
          a1_2 = *(const f2*)&As[buf][ty * 2 + 1][kn];
          b0_2 = *(const f4*)&Bs[buf][kn][tx * 4];
          b1_2 = *(const f4*)&Bs[buf][kn + 1][tx * 4];
        }
        #pragma unroll
        for (int j = 0; j < 4; ++j) {
          acc[0][j] = fmaf(a0_0[0], b0_0[j], acc[0][j]);
          acc[0][j] = fmaf(a0_0[1], b1_0[j], acc[0][j]);
          acc[1][j] = fmaf(a1_0[0], b0_0[j], acc[1][j]);
          acc[1][j] = fmaf(a1_0[1], b1_0[j], acc[1][j]);
        }
        a0_0 = a0_1; a1_0 = a1_1; b0_0 = b0_1; b1_0 = b1_1;
        a0_1 = a0_2; a1_1 = a1_2; b0_1 = b0_2; b1_1 = b1_2;
      }
      buf ^= 1;
    }
  }

  const int r0 = J.m0 + ty * 2, c0 = J.n0 + tx * 4;
  f4 bias = {0.f, 0.f, 0.f, 0.f};
  if (J.b1) bias += *(const f4*)(J.b1 + c0);
  if (J.b2) bias += *(const f4*)(J.b2 + c0);
  f4 v0, v1;
  #pragma unroll
  for (int j = 0; j < 4; ++j) { v0[j] = acc[0][j] + bias[j]; v1[j] = acc[1][j] + bias[j]; }
  if (J.addm) { v0 += am0; v1 += am1; }
  if (J.doElu) {
    #pragma unroll
    for (int j = 0; j < 4; ++j) { v0[j] = eluf(v0[j]); v1[j] = eluf(v1[j]); }
  }
  st_c(J.out + (size_t)r0 * J.N + c0, v0);
  st_c(J.out + (size_t)(r0 + 1) * J.N + c0, v1);

  if (J.stats) {   // deterministic per-64-row-tile column partials
    float* Af = (float*)As;
    float* Bf = (float*)Bs;
    __syncthreads();
    #pragma unroll
    for (int j = 0; j < 4; ++j) {
      Af[ty * 64 + tx * 4 + j] = v0[j] + v1[j];
      Bf[ty * 64 + tx * 4 + j] = v0[j] * v0[j] + v1[j] * v1[j];
    }
    __syncthreads();
    if (tid < 64) {
      float S = 0.f, S2 = 0.f;
      #pragma unroll
      for (int y = 0; y < 32; ++y) { S += Af[y * 64 + tid]; S2 += Bf[y * 64 + tid]; }
      const int tm = J.m0 >> 6;
      stf_c(J.stats + tm * 1024 + J.n0 + tid, S);
      stf_c(J.stats + tm * 1024 + 512 + J.n0 + tid, S2);
    }
  }
}

__global__ __launch_bounds__(NTHR, 1) void larnn(Params P) {
  __shared__ float As[2][64][36];
  __shared__ float Bs[2][32][68];
  __shared__ float scl[H_], shf[H_];
  __shared__ float Qs[H_];
  __shared__ float sc_[8][16], aw_[8][16];

  const int bid = blockIdx.x, tid = threadIdx.x;
  unsigned g = 0;

  for (int t = 0; t < T_; ++t) {
    const float* xt = P.x + (size_t)t * B_ * F_;
    const int slot = (t - 1) & 15;

    // =========== P1: q | K-ring | V-ring | preA | out[t-1] ===========
    if (bid < 32) {
      if (t > 0) { prepP(P.stP, P.g_post, P.be_post, scl, shf, tid); __syncthreads(); }
      GJ J = {}; J.A1 = xt; J.lda1 = F_; J.K1 = F_;
      if (t > 0) { J.A2 = P.hv; J.lda2 = H_; J.K2 = H_; J.nrm2 = 1; J.cg2 = 1; }
      J.W1 = P.Wq_in; J.W2 = P.Wq_in + (size_t)F_ * H_;
      J.b1 = P.bq_in; J.out = P.q; J.N = H_;
      J.m0 = (bid >> 3) * 64; J.n0 = (bid & 7) * 64; J.doElu = 1;
      gemm_tile(J, tid, As, Bs, scl, shf);
    } else if (bid < 64) {
      int l = bid - 32;
      GJ J = {}; J.A1 = P.c; J.lda1 = H_; J.K1 = H_; J.cg1 = 1;
      J.W1 = P.Wk; J.b1 = P.bk; J.out = P.Kbuf + (size_t)slot * BH_; J.N = H_;
      J.m0 = (l >> 3) * 64; J.n0 = (l & 7) * 64; J.doElu = 1;
      gemm_tile(J, tid, As, Bs, scl, shf);
    } else if (bid < 96) {
      int l = bid - 64;
      GJ J = {}; J.A1 = P.c; J.lda1 = H_; J.K1 = H_; J.cg1 = 1;
      J.W1 = P.Wv; J.b1 = P.bv; J.out = P.Vbuf + (size_t)slot * BH_; J.N = H_;
      J.m0 = (l >> 3) * 64; J.n0 = (l & 7) * 64; J.doElu = 1;
      gemm_tile(J, tid, As, Bs, scl, shf);
    } else if (bid < 224) {
      if (t > 0) { prepP(P.stP, P.g_post, P.be_post, scl, shf, tid); __syncthreads(); }
      const int ix = bid - 96;
      GJ J = {}; J.A1 = xt; J.lda1 = F_; J.K1 = F_;
      if (t > 0) { J.A2 = P.hv; J.lda2 = H_; J.K2 = H_; J.nrm2 = 1; J.cg2 = 1; }
      J.W1 = P.W_ih; J.W2 = P.W_hh;
      J.b1 = P.b_ih; J.b2 = P.b_ac; J.out = P.pre; J.N = H4_;
      J.m0 = (ix >> 5) * 64; J.n0 = (ix & 31) * 64;
      gemm_tile(J, tid, As, Bs, scl, shf);
    } else if (t > 0) {
      prepP(P.stP, P.g_post, P.be_post, scl, shf, tid);
      __syncthreads();
      const int rb0 = (bid - 224) * 8;
      for (int idx = tid; idx < 1024; idx += NTHR) {
        int r = rb0 + (idx >> 7), cc = (idx & 127) * 4;
        f4 hvv = ld_c(P.hv + (size_t)r * H_ + cc);
        f4 v;
        #pragma unroll
        for (int i = 0; i < 4; ++i) v[i] = hvv[i] * scl[cc + i] + shf[cc + i];
        *(f4*)(P.out + (size_t)(t - 1) * BH_ + (size_t)r * H_ + cc) = v;
      }
    }
    gbar(P.arr, P.gen, ++g);

    // =========== P2: Qh = q@Wq + bq ===========
    if (bid < 32) {
      GJ J = {}; J.A1 = P.q; J.lda1 = H_; J.K1 = H_; J.cg1 = 1;
      J.W1 = P.Wq; J.b1 = P.bq; J.out = P.Qh; J.N = H_;
      J.m0 = (bid >> 3) * 64; J.n0 = (bid & 7) * 64;
      gemm_tile(J, tid, As, Bs, scl, shf);
    }
    gbar(P.arr, P.gen, ++g);

    // =========== P3: attention (1 batch row / block) ===========
    {
      const int b = bid;
      const int nv = (t + 1 < W_) ? t + 1 : W_;
      if (tid < 128) *(f4*)&Qs[tid * 4] = ld_c(P.Qh + (size_t)b * H_ + tid * 4);
      __syncthreads();
      {
        const int p = tid >> 2, l4 = tid & 3;
        const int hh = p >> 4, w = p & 15;
        if (w < nv) {
          const int sl = (t - 1 - w) & 15;
          const float* kp = P.Kbuf + ((size_t)sl * B_ + b) * H_ + hh * 64 + l4 * 16;
          const float* qp = Qs + hh * 64 + l4 * 16;
          float s = 0.f;
          #pragma unroll
          for (int d = 0; d < 16; d += 4) {
            f4 kv = ld_c(kp + d);
            f4 qv = *(const f4*)(qp + d);
            s = fmaf(kv[0], qv[0], fmaf(kv[1], qv[1], fmaf(kv[2], qv[2], fmaf(kv[3], qv[3], s))));
          }
          s += __shfl_xor(s, 1); s += __shfl_xor(s, 2);
          if (l4 == 0) sc_[hh][w] = s * 0.125f;
        }
      }
      __syncthreads();
      if (tid < 8) {
        float mx = -1e30f;
        for (int w = 0; w < nv; ++w) mx = fmaxf(mx, sc_[tid][w]);
        float ss = 0.f;
        for (int w = 0; w < nv; ++w) { float e = expf(sc_[tid][w] - mx); aw_[tid][w] = e; ss += e; }
        float inv = 1.f / ss;
        for (int w = 0; w < nv; ++w) aw_[tid][w] *= inv;
      }
      __syncthreads();
      {
        const int j = tid, hh = j >> 6;
        float o = 0.f;
        for (int w = 0; w < nv; ++w) {
          const int sl = (t - 1 - w) & 15;
          o = fmaf(aw_[hh][w], ldf_c(P.Vbuf + ((size_t)sl * B_ + b) * H_ + j), o);
        }
        stf_c(P.ctx + (size_t)b * H_ + j, o);
      }
    }
    gbar(P.arr, P.gen, ++g);

    // =========== P4: attp = elu(ctx@Wo + bo) + BN partials ===========
    if (bid < 32) {
      GJ J = {}; J.A1 = P.ctx; J.lda1 = H_; J.K1 = H_; J.cg1 = 1;
      J.W1 = P.Wo; J.b1 = P.bo; J.doElu = 1;
      J.out = P.attp; J.stats = P.stA; J.N = H_;
      J.m0 = (bid >> 3) * 64; J.n0 = (bid & 7) * 64;
      gemm_tile(J, tid, As, Bs, scl, shf);
    }
    gbar(P.arr, P.gen, ++g);

    // =========== P5: pre += BN(attp)@W_ac ===========
    if (bid < 128) {
      prepA(P.stA, P.g_att, P.be_att, scl, shf, tid);
      __syncthreads();
      GJ J = {}; J.A1 = P.attp; J.lda1 = H_; J.K1 = H_; J.cg1 = 1; J.nrm1 = 1;
      J.W1 = P.W_ac; J.addm = P.pre; J.out = P.pre; J.N = H4_;
      J.m0 = (bid >> 5) * 64; J.n0 = (bid & 31) * 64;
      gemm_tile(J, tid, As, Bs, scl, shf);
    }
    gbar(P.arr, P.gen, ++g);

    // =========== P6: gates + c/hv + BN-post stats ===========
    if (bid < 64) {
      f4* rS = (f4*)As;
      f4* rQ = (f4*)Bs;
      const int sub = tid & 1, r = tid >> 1;
      const int c4 = bid * 8 + sub * 4;
      const size_t rb = (size_t)r * H4_;
      f4 p0 = ld_c(P.pre + rb + c4);
      f4 pf = ld_c(P.pre + rb + c4 + 512);
      f4 pi = ld_c(P.pre + rb + c4 + 1024);
      f4 po = ld_c(P.pre + rb + c4 + 1536);
      const size_t ci = (size_t)r * H_ + c4;
      f4 cold = ld_c(P.c + ci);
      f4 cn, hvv;
      #pragma unroll
      for (int i = 0; i < 4; ++i) {
        float iv = tanhf(p0[i]);
        float fg = sigf(pf[i]), ig = sigf(pi[i]), og = sigf(po[i]);
        cn[i] = iv * ig + cold[i] * fg;
        hvv[i] = og * eluf(cn[i]);
      }
      st_c(P.c + ci, cn);
      st_c(P.hv + ci, hvv);
      rS[sub * 256 + r] = hvv;
      rQ[sub * 256 + r] = hvv * hvv;
      __syncthreads();
      for (int s2 = 128; s2 > 0; s2 >>= 1) {
        if (r < s2) {
          rS[sub * 256 + r] += rS[sub * 256 + r + s2];
          rQ[sub * 256 + r] += rQ[sub * 256 + r + s2];
        }
        __syncthreads();
      }
      if (r == 0) {
        f4 S = rS[sub * 256], Q2 = rQ[sub * 256];
        #pragma unroll
        for (int i = 0; i < 4; ++i) { stf_c(P.stP + c4 + i, S[i]); stf_c(P.stP + 512 + c4 + i, Q2[i]); }
      }
    }
    gbar(P.arr, P.gen, ++g);
  }

  // =========== final out-copy for t = 127 ===========
  if (bid >= 224) {
    prepP(P.stP, P.g_post, P.be_post, scl, shf, tid);
    __syncthreads();
    const int rb0 = (bid - 224) * 8;
    for (int idx = tid; idx < 1024; idx += NTHR) {
      int r = rb0 + (idx >> 7), cc = (idx & 127) * 4;
      f4 hvv = ld_c(P.hv + (size_t)r * H_ + cc);
      f4 v;
      #pragma unroll
      for (int i = 0; i < 4; ++i) v[i] = hvv[i] * scl[cc + i] + shf[cc + i];
      *(f4*)(P.out + (size_t)127 * BH_ + (size_t)r * H_ + cc) = v;
    }
  }
}

#define SYNC_UINTS (32 + NBLK * FSTRIDE)   // gen line + 256 padded flags

__global__ __launch_bounds__(256) void pinit(float* c, unsigned* sync) {
  const int i = blockIdx.x * 256 + threadIdx.x;
  if (i < BH_) c[i] = 0.f;
  if (i < SYNC_UINTS) sync[i] = 0u;
}

extern "C" void kernel_launch(void* const* d_in, const int* in_sizes, int n_in,
                              void* d_out, int out_size, void* d_ws, size_t ws_size,
                              hipStream_t stream) {
  Params P;
  P.x      = (const float*)d_in[0];
  P.W_ih   = (const float*)d_in[1];
  P.b_ih   = (const float*)d_in[2];
  P.W_hh   = (const float*)d_in[3];
  P.Wq_in  = (const float*)d_in[4];
  P.bq_in  = (const float*)d_in[5];
  P.Wq     = (const float*)d_in[6];
  P.bq     = (const float*)d_in[7];
  P.Wk     = (const float*)d_in[8];
  P.bk     = (const float*)d_in[9];
  P.Wv     = (const float*)d_in[10];
  P.bv     = (const float*)d_in[11];
  P.Wo     = (const float*)d_in[12];
  P.bo     = (const float*)d_in[13];
  P.W_ac   = (const float*)d_in[14];
  P.b_ac   = (const float*)d_in[15];
  P.g_att  = (const float*)d_in[16];
  P.be_att = (const float*)d_in[17];
  P.g_post = (const float*)d_in[18];
  P.be_post= (const float*)d_in[19];
  P.out    = (float*)d_out;

  unsigned* sync = (unsigned*)d_ws;
  P.gen = sync;                    // own 128B line
  P.arr = sync + 32;               // 256 flags, 128B stride
  float* fb = (float*)d_ws + SYNC_UINTS;
  P.c    = fb;                 fb += BH_;
  P.q    = fb;                 fb += BH_;
  P.Qh   = fb;                 fb += BH_;
  P.ctx  = fb;                 fb += BH_;
  P.attp = fb;                 fb += BH_;
  P.hv   = fb;                 fb += BH_;
  P.pre  = fb;                 fb += (size_t)B_ * H4_;
  P.Kbuf = fb;                 fb += (size_t)W_ * BH_;
  P.Vbuf = fb;                 fb += (size_t)W_ * BH_;
  P.stA  = fb;                 fb += 4096;
  P.stP  = fb;                 fb += 1024;

  pinit<<<(BH_ + 255) / 256, 256, 0, stream>>>(P.c, sync);
  larnn<<<NBLK, NTHR, 0, stream>>>(P);
}

// Round 16
// 15822.514 us; speedup vs baseline: 2.1259x; 1.0558x over previous
//
#include <hip/hip_runtime.h>
#include <math.h>

// ============================================================================
// LARNN forward, MI355X — persistent kernel, fence-free sc1.
// ALL-F32 (bf16 diverges — chaotic recurrence). Deterministic BN stats.
// Round 16 = round-11 skeleton, retiled for 2-blocks/CU occupancy:
//   512 blocks x 512 threads, __launch_bounds__(512,4) -> <=128 VGPR ->
//   16 waves/CU (vs r11's 8). Tiles 64x32, microtile 2x2, f2 B-path.
//   gemm_tile slab structure identical (1 sync/slab, named-value prefetch).
//   r15 falsified LDS-latency theory; this tests occupancy as the limiter.
// ============================================================================

#define T_  128
#define B_  256
#define F_  128
#define H_  512
#define W_  16
#define H4_ 2048
#define EPS_ 1e-5f
#define BH_ (B_*H_)
#define NBLK 512
#define NTHR 512
#define FSTRIDE 32   // uints per flag (128B line)

typedef __attribute__((ext_vector_type(4))) float f4;
typedef __attribute__((ext_vector_type(2))) float f2;
typedef unsigned long long u64;

__device__ __forceinline__ float eluf(float x){ return x > 0.f ? x : expf(x) - 1.f; }
__device__ __forceinline__ float sigf(float x){ return 1.f / (1.f + expf(-x)); }

// ---- LLC-coherent (sc1) relaxed accessors: no cache maintenance emitted ----
__device__ __forceinline__ f4 ld_c(const float* p) {
  union { f4 v; u64 q[2]; } u;
  u.q[0] = __hip_atomic_load((const u64*)p,     __ATOMIC_RELAXED, __HIP_MEMORY_SCOPE_AGENT);
  u.q[1] = __hip_atomic_load((const u64*)p + 1, __ATOMIC_RELAXED, __HIP_MEMORY_SCOPE_AGENT);
  return u.v;
}
__device__ __forceinline__ void st_c(float* p, f4 v) {
  union { f4 v; u64 q[2]; } u; u.v = v;
  __hip_atomic_store((u64*)p,     u.q[0], __ATOMIC_RELAXED, __HIP_MEMORY_SCOPE_AGENT);
  __hip_atomic_store((u64*)p + 1, u.q[1], __ATOMIC_RELAXED, __HIP_MEMORY_SCOPE_AGENT);
}
__device__ __forceinline__ f2 ld2_c(const float* p) {
  union { u64 q; f2 v; } u;
  u.q = __hip_atomic_load((const u64*)p, __ATOMIC_RELAXED, __HIP_MEMORY_SCOPE_AGENT);
  return u.v;
}
__device__ __forceinline__ void st2_c(float* p, f2 v) {
  union { f2 v; u64 q; } u; u.v = v;
  __hip_atomic_store((u64*)p, u.q, __ATOMIC_RELAXED, __HIP_MEMORY_SCOPE_AGENT);
}
__device__ __forceinline__ float ldf_c(const float* p) {
  unsigned u = __hip_atomic_load((const unsigned*)p, __ATOMIC_RELAXED, __HIP_MEMORY_SCOPE_AGENT);
  return __uint_as_float(u);
}
__device__ __forceinline__ void stf_c(float* p, float v) {
  __hip_atomic_store((unsigned*)p, __float_as_uint(v), __ATOMIC_RELAXED, __HIP_MEMORY_SCOPE_AGENT);
}

struct Params {
  const float *x, *W_ih, *b_ih, *W_hh, *Wq_in, *bq_in, *Wq, *bq, *Wk, *bk,
              *Wv, *bv, *Wo, *bo, *W_ac, *b_ac, *g_att, *be_att, *g_post, *be_post;
  float *out, *c, *q, *Qh, *ctx, *attp, *hv, *pre, *Kbuf, *Vbuf, *stA, *stP;
  unsigned *gen, *arr;
};

// Barrier: flag store + block-0 parallel aggregation (512 thr : 512 flags) +
// gen release. Same structure as r11, scaled to NBLK=512.
__device__ __forceinline__ void gbar(unsigned* arr, unsigned* gen, unsigned g) {
  asm volatile("s_waitcnt vmcnt(0) lgkmcnt(0)" ::: "memory");
  __syncthreads();
  const int tid = threadIdx.x;
  if (tid == 0)
    __hip_atomic_store(&arr[blockIdx.x * FSTRIDE], g, __ATOMIC_RELAXED, __HIP_MEMORY_SCOPE_AGENT);
  if (blockIdx.x == 0) {
    if (tid < NBLK) {
      while (__hip_atomic_load(&arr[tid * FSTRIDE], __ATOMIC_RELAXED, __HIP_MEMORY_SCOPE_AGENT) < g)
        __builtin_amdgcn_s_sleep(1);
    }
    __syncthreads();
    if (tid == 0)
      __hip_atomic_store(gen, g, __ATOMIC_RELAXED, __HIP_MEMORY_SCOPE_AGENT);
  } else {
    if (tid == 0) {
      while (__hip_atomic_load(gen, __ATOMIC_RELAXED, __HIP_MEMORY_SCOPE_AGENT) < g)
        __builtin_amdgcn_s_sleep(1);
    }
  }
  __syncthreads();
}

// BN scale/shift from single-partial stats stP[2][512] (gates output).
__device__ __forceinline__ void prepP(const float* stP, const float* gn, const float* be,
                                      float* scl, float* shf, int tid) {
  if (tid < H_) {
    float S  = ldf_c(stP + tid);
    float S2 = ldf_c(stP + H_ + tid);
    float mu  = S * (1.f / B_);
    float var = S2 * (1.f / B_) - mu * mu;
    float sc  = rsqrtf(var + EPS_) * gn[tid];
    scl[tid] = sc; shf[tid] = be[tid] - mu * sc;
  }
}

// BN scale/shift from 4-way partial stats stA[4][2][512] (Wo GEMM output).
__device__ __forceinline__ void prepA(const float* stA, const float* gn, const float* be,
                                      float* scl, float* shf, int tid) {
  if (tid < H_) {
    float S  = ldf_c(stA + tid) + ldf_c(stA + 1024 + tid) + ldf_c(stA + 2048 + tid) + ldf_c(stA + 3072 + tid);
    float S2 = ldf_c(stA + 512 + tid) + ldf_c(stA + 1536 + tid) + ldf_c(stA + 2560 + tid) + ldf_c(stA + 3584 + tid);
    float mu  = S * (1.f / B_);
    float var = S2 * (1.f / B_) - mu * mu;
    float sc  = rsqrtf(var + EPS_) * gn[tid];
    scl[tid] = sc; shf[tid] = be[tid] - mu * sc;
  }
}

// ---------------------------------------------------------------------------
// 64x32 output tile, K-concat of up to 2 segments, 512 threads, 2x2 microtile.
// LDS double-buffered; ONE sync per 32-k slab. Staging prefetch: A depth-2
// (f4), B depth-1 (f2) — named values only (register arrays spill, rule #20).
// Per-element FMA order identical to r11 (same k-order, same slab order).
// ---------------------------------------------------------------------------
struct GJ {
  const float* A1; int lda1; int K1; int nrm1; int cg1;
  const float* A2; int lda2; int K2; int nrm2; int cg2;
  const float* W1; const float* W2;    // [K][N] row-major, stride N (plain)
  const float* b1; const float* b2; const float* addm;
  float* out; float* stats;
  int N; int m0; int n0; int doElu;
};

__device__ void gemm_tile(const GJ& J, int tid,
                          float (*As)[64][36], float (*Bs)[32][36],
                          const float* scl, const float* shf) {
  const int arow = tid >> 3, akq = (tid & 7) * 4;    // A stage: 1 f4/thread
  const int bkk = tid >> 4, bnn = (tid & 15) * 2;    // B stage: 1 f2/thread
  const int ty = tid >> 4, tx = tid & 15;            // microtile 2x2

  float acc[2][2] = {{0.f,0.f},{0.f,0.f}};

  f2 am0 = {0.f,0.f}, am1 = {0.f,0.f};
  if (J.addm) {
    am0 = ld2_c(J.addm + (size_t)(J.m0 + ty * 2)     * J.N + J.n0 + tx * 2);
    am1 = ld2_c(J.addm + (size_t)(J.m0 + ty * 2 + 1) * J.N + J.n0 + tx * 2);
  }

  int buf = 0;
  for (int s = 0; s < 2; ++s) {
    const float* A = s ? J.A2 : J.A1;
    if (!A) break;
    const float* Wp  = s ? J.W2 : J.W1;
    const int K      = s ? J.K2 : J.K1;
    const int lda    = s ? J.lda2 : J.lda1;
    const int nrm    = s ? J.nrm2 : J.nrm1;
    const int cg     = s ? J.cg2 : J.cg1;
    const int nsl    = K >> 5;

    const float* aBase = A + (size_t)(J.m0 + arow) * lda + akq;
    const float* wBase = Wp + (size_t)bkk * J.N + J.n0 + bnn;
    const size_t wSlab = (size_t)32 * J.N;

    // prologue: named-value prefetch (depth 2 for A, 1 for B)
    f4 aN1 = cg ? ld_c(aBase) : *(const f4*)aBase;
    f4 aN2 = (nsl > 1) ? (cg ? ld_c(aBase + 32) : *(const f4*)(aBase + 32)) : aN1;
    f2 bN1 = *(const f2*)wBase;

    for (int sl = 0; sl < nsl; ++sl) {
      f4 aCur = aN1; aN1 = aN2;
      f2 bCur = bN1;
      if (sl + 2 < nsl) {
        const float* ap = aBase + (size_t)(sl + 2) * 32;
        aN2 = cg ? ld_c(ap) : *(const f4*)ap;
      }
      if (sl + 1 < nsl) bN1 = *(const f2*)(wBase + (size_t)(sl + 1) * wSlab);
      if (nrm) {
        #pragma unroll
        for (int i = 0; i < 4; ++i) {
          int gk = sl * 32 + akq + i;
          aCur[i] = aCur[i] * scl[gk] + shf[gk];
        }
      }
      *(f4*)&As[buf][arow][akq] = aCur;
      *(f2*)&Bs[buf][bkk][bnn] = bCur;
      __syncthreads();
      #pragma unroll
      for (int k = 0; k < 32; k += 2) {
        f2 a0 = *(const f2*)&As[buf][ty * 2][k];
        f2 a1 = *(const f2*)&As[buf][ty * 2 + 1][k];
        f2 b0 = *(const f2*)&Bs[buf][k][tx * 2];
        f2 b1 = *(const f2*)&Bs[buf][k + 1][tx * 2];
        acc[0][0] = fmaf(a0[0], b0[0], acc[0][0]);
        acc[0][1] = fmaf(a0[0], b0[1], acc[0][1]);
        acc[0][0] = fmaf(a0[1], b1[0], acc[0][0]);
        acc[0][1] = fmaf(a0[1], b1[1], acc[0][1]);
        acc[1][0] = fmaf(a1[0], b0[0], acc[1][0]);
        acc[1][1] = fmaf(a1[0], b0[1], acc[1][1]);
        acc[1][0] = fmaf(a1[1], b1[0], acc[1][0]);
        acc[1][1] = fmaf(a1[1], b1[1], acc[1][1]);
      }
      buf ^= 1;
    }
  }

  const int r0 = J.m0 + ty * 2, c0 = J.n0 + tx * 2;
  f2 bias = {0.f, 0.f};
  if (J.b1) bias += *(const f2*)(J.b1 + c0);
  if (J.b2) bias += *(const f2*)(J.b2 + c0);
  f2 v0, v1;
  v0[0] = acc[0][0] + bias[0]; v0[1] = acc[0][1] + bias[1];
  v1[0] = acc[1][0] + bias[0]; v1[1] = acc[1][1] + bias[1];
  if (J.addm) { v0 += am0; v1 += am1; }
  if (J.doElu) {
    v0[0] = eluf(v0[0]); v0[1] = eluf(v0[1]);
    v1[0] = eluf(v1[0]); v1[1] = eluf(v1[1]);
  }
  st2_c(J.out + (size_t)r0 * J.N + c0, v0);
  st2_c(J.out + (size_t)(r0 + 1) * J.N + c0, v1);

  if (J.stats) {   // deterministic per-64-row-tile column partials (32 cols)
    float* Af = (float*)As;
    float* Bf = (float*)Bs;
    __syncthreads();
    Af[ty * 32 + tx * 2]     = v0[0] + v1[0];
    Af[ty * 32 + tx * 2 + 1] = v0[1] + v1[1];
    Bf[ty * 32 + tx * 2]     = v0[0] * v0[0] + v1[0] * v1[0];
    Bf[ty * 32 + tx * 2 + 1] = v0[1] * v0[1] + v1[1] * v1[1];
    __syncthreads();
    if (tid < 32) {
      float S = 0.f, S2 = 0.f;
      #pragma unroll
      for (int y = 0; y < 32; ++y) { S += Af[y * 32 + tid]; S2 += Bf[y * 32 + tid]; }
      const int tm = J.m0 >> 6;
      stf_c(J.stats + tm * 1024 + J.n0 + tid, S);
      stf_c(J.stats + tm * 1024 + 512 + J.n0 + tid, S2);
    }
  }
}

__global__ __launch_bounds__(NTHR, 4) void larnn(Params P) {
  __shared__ float As[2][64][36];
  __shared__ float Bs[2][32][36];
  __shared__ float scl[H_], shf[H_];
  __shared__ float Qs[H_];
  __shared__ float sc_[8][16], aw_[8][16];

  const int bid = blockIdx.x, tid = threadIdx.x;
  unsigned g = 0;

  for (int t = 0; t < T_; ++t) {
    const float* xt = P.x + (size_t)t * B_ * F_;
    const int slot = (t - 1) & 15;

    // ===== P1: q[0,64) | K[64,128) | V[128,192) | preHF[192,448) | copy[448,480) =====
    if (bid < 64) {
      if (t > 0) { prepP(P.stP, P.g_post, P.be_post, scl, shf, tid); __syncthreads(); }
      GJ J = {}; J.A1 = xt; J.lda1 = F_; J.K1 = F_;
      if (t > 0) { J.A2 = P.hv; J.lda2 = H_; J.K2 = H_; J.nrm2 = 1; J.cg2 = 1; }
      J.W1 = P.Wq_in; J.W2 = P.Wq_in + (size_t)F_ * H_;
      J.b1 = P.bq_in; J.out = P.q; J.N = H_;
      J.m0 = (bid >> 4) * 64; J.n0 = (bid & 15) * 32; J.doElu = 1;
      gemm_tile(J, tid, As, Bs, scl, shf);
    } else if (bid < 128) {
      int l = bid - 64;
      GJ J = {}; J.A1 = P.c; J.lda1 = H_; J.K1 = H_; J.cg1 = 1;
      J.W1 = P.Wk; J.b1 = P.bk; J.out = P.Kbuf + (size_t)slot * BH_; J.N = H_;
      J.m0 = (l >> 4) * 64; J.n0 = (l & 15) * 32; J.doElu = 1;
      gemm_tile(J, tid, As, Bs, scl, shf);
    } else if (bid < 192) {
      int l = bid - 128;
      GJ J = {}; J.A1 = P.c; J.lda1 = H_; J.K1 = H_; J.cg1 = 1;
      J.W1 = P.Wv; J.b1 = P.bv; J.out = P.Vbuf + (size_t)slot * BH_; J.N = H_;
      J.m0 = (l >> 4) * 64; J.n0 = (l & 15) * 32; J.doElu = 1;
      gemm_tile(J, tid, As, Bs, scl, shf);
    } else if (bid < 448) {
      if (t > 0) { prepP(P.stP, P.g_post, P.be_post, scl, shf, tid); __syncthreads(); }
      const int ix = bid - 192;
      GJ J = {}; J.A1 = xt; J.lda1 = F_; J.K1 = F_;
      if (t > 0) { J.A2 = P.hv; J.lda2 = H_; J.K2 = H_; J.nrm2 = 1; J.cg2 = 1; }
      J.W1 = P.W_ih; J.W2 = P.W_hh;
      J.b1 = P.b_ih; J.b2 = P.b_ac; J.out = P.pre; J.N = H4_;
      J.m0 = (ix >> 6) * 64; J.n0 = (ix & 63) * 32;
      gemm_tile(J, tid, As, Bs, scl, shf);
    } else if (bid < 480 && t > 0) {
      prepP(P.stP, P.g_post, P.be_post, scl, shf, tid);
      __syncthreads();
      const int rb0 = (bid - 448) * 8;
      for (int idx = tid; idx < 1024; idx += NTHR) {
        int r = rb0 + (idx >> 7), cc = (idx & 127) * 4;
        f4 hvv = ld_c(P.hv + (size_t)r * H_ + cc);
        f4 v;
        #pragma unroll
        for (int i = 0; i < 4; ++i) v[i] = hvv[i] * scl[cc + i] + shf[cc + i];
        *(f4*)(P.out + (size_t)(t - 1) * BH_ + (size_t)r * H_ + cc) = v;
      }
    }
    gbar(P.arr, P.gen, ++g);

    // =========== P2: Qh = q@Wq + bq (64 blocks) ===========
    if (bid < 64) {
      GJ J = {}; J.A1 = P.q; J.lda1 = H_; J.K1 = H_; J.cg1 = 1;
      J.W1 = P.Wq; J.b1 = P.bq; J.out = P.Qh; J.N = H_;
      J.m0 = (bid >> 4) * 64; J.n0 = (bid & 15) * 32;
      gemm_tile(J, tid, As, Bs, scl, shf);
    }
    gbar(P.arr, P.gen, ++g);

    // =========== P3: attention (1 batch row / block, bid < 256) ===========
    if (bid < B_) {
      const int b = bid;
      const int nv = (t + 1 < W_) ? t + 1 : W_;
      if (tid < 128) *(f4*)&Qs[tid * 4] = ld_c(P.Qh + (size_t)b * H_ + tid * 4);
      __syncthreads();
      {
        const int p = tid >> 2, l4 = tid & 3;
        const int hh = p >> 4, w = p & 15;
        if (w < nv) {
          const int sl = (t - 1 - w) & 15;
          const float* kp = P.Kbuf + ((size_t)sl * B_ + b) * H_ + hh * 64 + l4 * 16;
          const float* qp = Qs + hh * 64 + l4 * 16;
          float s = 0.f;
          #pragma unroll
          for (int d = 0; d < 16; d += 4) {
            f4 kv = ld_c(kp + d);
            f4 qv = *(const f4*)(qp + d);
            s = fmaf(kv[0], qv[0], fmaf(kv[1], qv[1], fmaf(kv[2], qv[2], fmaf(kv[3], qv[3], s))));
          }
          s += __shfl_xor(s, 1); s += __shfl_xor(s, 2);
          if (l4 == 0) sc_[hh][w] = s * 0.125f;
        }
      }
      __syncthreads();
      if (tid < 8) {
        float mx = -1e30f;
        for (int w = 0; w < nv; ++w) mx = fmaxf(mx, sc_[tid][w]);
        float ss = 0.f;
        for (int w = 0; w < nv; ++w) { float e = expf(sc_[tid][w] - mx); aw_[tid][w] = e; ss += e; }
        float inv = 1.f / ss;
        for (int w = 0; w < nv; ++w) aw_[tid][w] *= inv;
      }
      __syncthreads();
      {
        const int j = tid, hh = j >> 6;
        float o = 0.f;
        for (int w = 0; w < nv; ++w) {
          const int sl = (t - 1 - w) & 15;
          o = fmaf(aw_[hh][w], ldf_c(P.Vbuf + ((size_t)sl * B_ + b) * H_ + j), o);
        }
        stf_c(P.ctx + (size_t)b * H_ + j, o);
      }
    }
    gbar(P.arr, P.gen, ++g);

    // =========== P4: attp = elu(ctx@Wo + bo) + BN partials (64 blocks) ===========
    if (bid < 64) {
      GJ J = {}; J.A1 = P.ctx; J.lda1 = H_; J.K1 = H_; J.cg1 = 1;
      J.W1 = P.Wo; J.b1 = P.bo; J.doElu = 1;
      J.out = P.attp; J.stats = P.stA; J.N = H_;
      J.m0 = (bid >> 4) * 64; J.n0 = (bid & 15) * 32;
      gemm_tile(J, tid, As, Bs, scl, shf);
    }
    gbar(P.arr, P.gen, ++g);

    // =========== P5: pre += BN(attp)@W_ac (256 blocks) ===========
    if (bid < 256) {
      prepA(P.stA, P.g_att, P.be_att, scl, shf, tid);
      __syncthreads();
      GJ J = {}; J.A1 = P.attp; J.lda1 = H_; J.K1 = H_; J.cg1 = 1; J.nrm1 = 1;
      J.W1 = P.W_ac; J.addm = P.pre; J.out = P.pre; J.N = H4_;
      J.m0 = (bid >> 6) * 64; J.n0 = (bid & 63) * 32;
      gemm_tile(J, tid, As, Bs, scl, shf);
    }
    gbar(P.arr, P.gen, ++g);

    // =========== P6: gates + c/hv + BN-post stats (64 blocks) ===========
    if (bid < 64) {
      f4* rS = (f4*)As;
      f4* rQ = (f4*)Bs;
      const int sub = tid & 1, r = tid >> 1;
      const int c4 = bid * 8 + sub * 4;
      const size_t rb = (size_t)r * H4_;
      f4 p0 = ld_c(P.pre + rb + c4);
      f4 pf = ld_c(P.pre + rb + c4 + 512);
      f4 pi = ld_c(P.pre + rb + c4 + 1024);
      f4 po = ld_c(P.pre + rb + c4 + 1536);
      const size_t ci = (size_t)r * H_ + c4;
      f4 cold = ld_c(P.c + ci);
      f4 cn, hvv;
      #pragma unroll
      for (int i = 0; i < 4; ++i) {
        float iv = tanhf(p0[i]);
        float fg = sigf(pf[i]), ig = sigf(pi[i]), og = sigf(po[i]);
        cn[i] = iv * ig + cold[i] * fg;
        hvv[i] = og * eluf(cn[i]);
      }
      st_c(P.c + ci, cn);
      st_c(P.hv + ci, hvv);
      rS[sub * 256 + r] = hvv;
      rQ[sub * 256 + r] = hvv * hvv;
      __syncthreads();
      for (int s2 = 128; s2 > 0; s2 >>= 1) {
        if (r < s2) {
          rS[sub * 256 + r] += rS[sub * 256 + r + s2];
          rQ[sub * 256 + r] += rQ[sub * 256 + r + s2];
        }
        __syncthreads();
      }
      if (r == 0) {
        f4 S = rS[sub * 256], Q2 = rQ[sub * 256];
        #pragma unroll
        for (int i = 0; i < 4; ++i) { stf_c(P.stP + c4 + i, S[i]); stf_c(P.stP + 512 + c4 + i, Q2[i]); }
      }
    }
    gbar(P.arr, P.gen, ++g);
  }

  // =========== final out-copy for t = 127 ===========
  if (bid >= 448 && bid < 480) {
    prepP(P.stP, P.g_post, P.be_post, scl, shf, tid);
    __syncthreads();
    const int rb0 = (bid - 448) * 8;
    for (int idx = tid; idx < 1024; idx += NTHR) {
      int r = rb0 + (idx >> 7), cc = (idx & 127) * 4;
      f4 hvv = ld_c(P.hv + (size_t)r * H_ + cc);
      f4 v;
      #pragma unroll
      for (int i = 0; i < 4; ++i) v[i] = hvv[i] * scl[cc + i] + shf[cc + i];
      *(f4*)(P.out + (size_t)127 * BH_ + (size_t)r * H_ + cc) = v;
    }
  }
}

#define SYNC_UINTS (32 + NBLK * FSTRIDE)   // gen line + 512 padded flags

__global__ __launch_bounds__(256) void pinit(float* c, unsigned* sync) {
  const int i = blockIdx.x * 256 + threadIdx.x;
  if (i < BH_) c[i] = 0.f;
  if (i < SYNC_UINTS) sync[i] = 0u;
}

extern "C" void kernel_launch(void* const* d_in, const int* in_sizes, int n_in,
                              void* d_out, int out_size, void* d_ws, size_t ws_size,
                              hipStream_t stream) {
  Params P;
  P.x      = (const float*)d_in[0];
  P.W_ih   = (const float*)d_in[1];
  P.b_ih   = (const float*)d_in[2];
  P.W_hh   = (const float*)d_in[3];
  P.Wq_in  = (const float*)d_in[4];
  P.bq_in  = (const float*)d_in[5];
  P.Wq     = (const float*)d_in[6];
  P.bq     = (const float*)d_in[7];
  P.Wk     = (const float*)d_in[8];
  P.bk     = (const float*)d_in[9];
  P.Wv     = (const float*)d_in[10];
  P.bv     = (const float*)d_in[11];
  P.Wo     = (const float*)d_in[12];
  P.bo     = (const float*)d_in[13];
  P.W_ac   = (const float*)d_in[14];
  P.b_ac   = (const float*)d_in[15];
  P.g_att  = (const float*)d_in[16];
  P.be_att = (const float*)d_in[17];
  P.g_post = (const float*)d_in[18];
  P.be_post= (const float*)d_in[19];
  P.out    = (float*)d_out;

  unsigned* sync = (unsigned*)d_ws;
  P.gen = sync;                    // own 128B line
  P.arr = sync + 32;               // 512 flags, 128B stride
  float* fb = (float*)d_ws + SYNC_UINTS;
  P.c    = fb;                 fb += BH_;
  P.q    = fb;                 fb += BH_;
  P.Qh   = fb;                 fb += BH_;
  P.ctx  = fb;                 fb += BH_;
  P.attp = fb;                 fb += BH_;
  P.hv   = fb;                 fb += BH_;
  P.pre  = fb;                 fb += (size_t)B_ * H4_;
  P.Kbuf = fb;                 fb += (size_t)W_ * BH_;
  P.Vbuf = fb;                 fb += (size_t)W_ * BH_;
  P.stA  = fb;                 fb += 4096;
  P.stP  = fb;                 fb += 1024;

  pinit<<<(BH_ + 255) / 256, 256, 0, stream>>>(P.c, sync);
  larnn<<<NBLK, NTHR, 0, stream>>>(P);
}